// Round 1
// baseline (7183.897 us; speedup 1.0000x reference)
//
#include <hip/hip_runtime.h>
#include <math.h>

#define B_   8
#define L_   1024
#define DIN_ 32
#define D_   512
#define H_   8
#define NL_  6
#define FF_  64
#define DK_  64
#define M_   (B_*L_)   // 8192

#define PE_COEF (-0.017988946039015984f)   // -ln(10000)/512

// ---------------- block reduce (256 threads = 4 waves) ----------------
__device__ __forceinline__ float block_reduce_sum(float v, float* smem4) {
  #pragma unroll
  for (int off = 32; off > 0; off >>= 1) v += __shfl_down(v, off, 64);
  int wid = threadIdx.x >> 6;
  __syncthreads();                       // protect smem4 reuse across calls
  if ((threadIdx.x & 63) == 0) smem4[wid] = v;
  __syncthreads();
  return smem4[0] + smem4[1] + smem4[2] + smem4[3];
}

// ---------------- embedding MLP stage 1 + LayerNorm ----------------
// out[m,:] = LN(relu(x[m,:] @ W1 + b1)) * g + beta
__global__ void emb1_ln_kernel(const float* __restrict__ x, const float* __restrict__ W1,
                               const float* __restrict__ b1, const float* __restrict__ g,
                               const float* __restrict__ beta, float* __restrict__ out) {
  __shared__ float xs[DIN_];
  __shared__ float red[4];
  int m = blockIdx.x;
  int tid = threadIdx.x;
  if (tid < DIN_) xs[tid] = x[m*DIN_ + tid];
  __syncthreads();
  float v[2];
  #pragma unroll
  for (int r = 0; r < 2; ++r) {
    int n = tid + r*256;
    float acc = b1[n];
    #pragma unroll
    for (int k = 0; k < DIN_; ++k) acc += xs[k] * W1[k*D_ + n];
    v[r] = fmaxf(acc, 0.f);
  }
  float mean = block_reduce_sum(v[0] + v[1], red) * (1.f/D_);
  float d0 = v[0] - mean, d1 = v[1] - mean;
  float var = block_reduce_sum(d0*d0 + d1*d1, red) * (1.f/D_);
  float rstd = rsqrtf(var + 1e-5f);
  out[(size_t)m*D_ + tid]       = d0*rstd*g[tid]       + beta[tid];
  out[(size_t)m*D_ + tid + 256] = d1*rstd*g[tid + 256] + beta[tid + 256];
}

// ---------------- residual add + LayerNorm ----------------
// out[m,:] = LN(hin[m,:] + res[m,:]) * g + b
__global__ void add_ln_kernel(const float* __restrict__ hin, const float* __restrict__ res,
                              const float* __restrict__ g, const float* __restrict__ b,
                              float* __restrict__ out) {
  __shared__ float red[4];
  int m = blockIdx.x;
  int tid = threadIdx.x;
  float v0 = hin[(size_t)m*D_ + tid]       + res[(size_t)m*D_ + tid];
  float v1 = hin[(size_t)m*D_ + tid + 256] + res[(size_t)m*D_ + tid + 256];
  float mean = block_reduce_sum(v0 + v1, red) * (1.f/D_);
  float d0 = v0 - mean, d1 = v1 - mean;
  float var = block_reduce_sum(d0*d0 + d1*d1, red) * (1.f/D_);
  float rstd = rsqrtf(var + 1e-5f);
  out[(size_t)m*D_ + tid]       = d0*rstd*g[tid]       + b[tid];
  out[(size_t)m*D_ + tid + 256] = d1*rstd*g[tid + 256] + b[tid + 256];
}

// ---------------- generic fp32 tiled GEMM, 64x64 tile, 4x4/thread ----------------
// EPI: 0 = none, 1 = +bias, 2 = relu(+bias), 3 = +bias + positional encoding
template<int EPI>
__global__ void gemm_kernel(const float* __restrict__ A, const float* __restrict__ Bm,
                            const float* __restrict__ bias, const float* __restrict__ extra,
                            float* __restrict__ C, int M, int N, int K) {
  __shared__ float As[16][65];   // As[k][m]
  __shared__ float Bs[16][65];   // Bs[k][n]
  int bm = blockIdx.y * 64;
  int bn = blockIdx.x * 64;
  int tid = threadIdx.x;
  int tx = tid & 15, ty = tid >> 4;
  float acc[4][4] = {};
  for (int k0 = 0; k0 < K; k0 += 16) {
    #pragma unroll
    for (int it = 0; it < 4; ++it) {
      int mm = (tid >> 4) + it*16;
      int kk = tid & 15;
      As[kk][mm] = A[(size_t)(bm + mm)*K + k0 + kk];
    }
    #pragma unroll
    for (int it = 0; it < 4; ++it) {
      int kk = (tid >> 6) + it*4;
      int nn = tid & 63;
      Bs[kk][nn] = Bm[(size_t)(k0 + kk)*N + bn + nn];
    }
    __syncthreads();
    #pragma unroll
    for (int kk = 0; kk < 16; ++kk) {
      float a[4], bb[4];
      #pragma unroll
      for (int ii = 0; ii < 4; ++ii) a[ii] = As[kk][ty*4 + ii];
      #pragma unroll
      for (int jj = 0; jj < 4; ++jj) bb[jj] = Bs[kk][tx*4 + jj];
      #pragma unroll
      for (int ii = 0; ii < 4; ++ii)
        #pragma unroll
        for (int jj = 0; jj < 4; ++jj)
          acc[ii][jj] += a[ii]*bb[jj];
    }
    __syncthreads();
  }
  #pragma unroll
  for (int ii = 0; ii < 4; ++ii) {
    int m = bm + ty*4 + ii;
    #pragma unroll
    for (int jj = 0; jj < 4; ++jj) {
      int n = bn + tx*4 + jj;
      float vv = acc[ii][jj];
      if (EPI >= 1) vv += bias[n];
      if (EPI == 2) vv = fmaxf(vv, 0.f);
      if (EPI == 3) {
        float t   = extra[m];                        // obs_time, flat [M]
        float fr  = __expf((float)(n & ~1) * PE_COEF);
        float arg = t * fr;
        vv += (n & 1) ? cosf(arg) : sinf(arg);
      }
      C[(size_t)m*N + n] = vv;
    }
  }
}

// ---------------- causal flash attention (fp32), 32-row Q tiles ----------------
// Q/K/V laid out [M, D] with head h in cols h*64..h*64+63.  O likewise.
__global__ void attn_kernel(const float* __restrict__ Q, const float* __restrict__ K,
                            const float* __restrict__ V, float* __restrict__ O) {
  __shared__ float Qs[32][65];
  __shared__ float Ks[32][65];
  __shared__ float Vs[32][65];
  __shared__ float Ps[32][65];
  int qt = blockIdx.x;            // q tile (32 rows)
  int bh = blockIdx.y;            // b*H + h
  int b  = bh >> 3, hh = bh & 7;
  int col0 = hh * DK_;
  int rowbase = b * L_;
  int tid = threadIdx.x;
  int i = tid >> 3;               // q row in tile, 0..31
  int c = tid & 7;                // col group, 0..7
  #pragma unroll
  for (int it = 0; it < 8; ++it) {
    int idx = tid + it*256;
    int r = idx >> 6, d = idx & 63;
    Qs[r][d] = Q[(size_t)(rowbase + qt*32 + r)*D_ + col0 + d] * 0.125f; // 1/sqrt(64) folded
  }
  float m_i = -1e30f, l_i = 0.f;
  float o[8];
  #pragma unroll
  for (int dd = 0; dd < 8; ++dd) o[dd] = 0.f;
  for (int kt = 0; kt <= qt; ++kt) {
    __syncthreads();              // protect Ks/Vs/Ps from previous iter reads
    #pragma unroll
    for (int it = 0; it < 8; ++it) {
      int idx = tid + it*256;
      int r = idx >> 6, d = idx & 63;
      Ks[r][d] = K[(size_t)(rowbase + kt*32 + r)*D_ + col0 + d];
      Vs[r][d] = V[(size_t)(rowbase + kt*32 + r)*D_ + col0 + d];
    }
    __syncthreads();
    int lq = qt*32 + i;
    float s0 = 0.f, s1 = 0.f, s2 = 0.f, s3 = 0.f;
    int j0 = c*4;
    #pragma unroll
    for (int d = 0; d < 64; ++d) {
      float qv = Qs[i][d];
      s0 += qv * Ks[j0+0][d];
      s1 += qv * Ks[j0+1][d];
      s2 += qv * Ks[j0+2][d];
      s3 += qv * Ks[j0+3][d];
    }
    float s[4] = {s0, s1, s2, s3};
    float mloc = -1e30f;
    #pragma unroll
    for (int jj = 0; jj < 4; ++jj) {
      if (kt*32 + j0 + jj > lq) s[jj] = -1e30f;
      mloc = fmaxf(mloc, s[jj]);
    }
    mloc = fmaxf(mloc, __shfl_xor(mloc, 1));
    mloc = fmaxf(mloc, __shfl_xor(mloc, 2));
    mloc = fmaxf(mloc, __shfl_xor(mloc, 4));
    float m_new = fmaxf(m_i, mloc);
    float corr = __expf(m_i - m_new);
    float psum = 0.f;
    #pragma unroll
    for (int jj = 0; jj < 4; ++jj) {
      float p = __expf(s[jj] - m_new);
      Ps[i][j0 + jj] = p;
      psum += p;
    }
    psum += __shfl_xor(psum, 1);
    psum += __shfl_xor(psum, 2);
    psum += __shfl_xor(psum, 4);
    l_i = l_i * corr + psum;
    m_i = m_new;
    #pragma unroll
    for (int dd = 0; dd < 8; ++dd) o[dd] *= corr;
    __syncthreads();              // Ps visible across the row's 8 threads
    #pragma unroll 4
    for (int j = 0; j < 32; ++j) {
      float p = Ps[i][j];
      #pragma unroll
      for (int dd = 0; dd < 8; ++dd)
        o[dd] += p * Vs[j][c*8 + dd];
    }
  }
  float inv = 1.f / l_i;
  #pragma unroll
  for (int dd = 0; dd < 8; ++dd)
    O[(size_t)(rowbase + qt*32 + i)*D_ + col0 + c*8 + dd] = o[dd] * inv;
}

// ---------------- host ----------------
extern "C" void kernel_launch(void* const* d_in, const int* in_sizes, int n_in,
                              void* d_out, int out_size, void* d_ws, size_t ws_size,
                              hipStream_t stream) {
  (void)in_sizes; (void)n_in; (void)out_size; (void)ws_size;
  const float* x      = (const float*)d_in[0];
  // d_in[1] = mask: exactly tril -> causal hard-coded
  const float* obs    = (const float*)d_in[2];
  const float* emb_w1 = (const float*)d_in[3];
  const float* emb_b1 = (const float*)d_in[4];
  const float* emb_g  = (const float*)d_in[5];
  const float* emb_be = (const float*)d_in[6];
  const float* emb_w2 = (const float*)d_in[7];
  const float* emb_b2 = (const float*)d_in[8];
  const float* wq  = (const float*)d_in[9];
  const float* wk  = (const float*)d_in[10];
  const float* wv  = (const float*)d_in[11];
  const float* wo  = (const float*)d_in[12];
  const float* bo  = (const float*)d_in[13];
  const float* fw1 = (const float*)d_in[14];
  const float* fb1 = (const float*)d_in[15];
  const float* fw2 = (const float*)d_in[16];
  const float* fb2 = (const float*)d_in[17];
  const float* g1  = (const float*)d_in[18];
  const float* b1  = (const float*)d_in[19];
  const float* g2  = (const float*)d_in[20];
  const float* b2  = (const float*)d_in[21];
  float* out = (float*)d_out;

  float* h  = (float*)d_ws;                 // [M, D]
  float* t0 = h  + (size_t)M_*D_;           // [M, D]  (GEMM out / attn out)
  float* q  = t0 + (size_t)M_*D_;           // [M, D]
  float* k  = q  + (size_t)M_*D_;           // [M, D]
  float* v  = k  + (size_t)M_*D_;           // [M, D]
  float* fh = v  + (size_t)M_*D_;           // [M, FF]

  dim3 gridD(D_/64, M_/64);
  dim3 gridF(FF_/64, M_/64);

  emb1_ln_kernel<<<M_, 256, 0, stream>>>(x, emb_w1, emb_b1, emb_g, emb_be, t0);
  gemm_kernel<3><<<gridD, 256, 0, stream>>>(t0, emb_w2, emb_b2, obs, h, M_, D_, D_);

  for (int i = 0; i < NL_; ++i) {
    const float* wq_i = wq + (size_t)i*D_*D_;
    const float* wk_i = wk + (size_t)i*D_*D_;
    const float* wv_i = wv + (size_t)i*D_*D_;
    const float* wo_i = wo + (size_t)i*D_*D_;
    gemm_kernel<0><<<gridD, 256, 0, stream>>>(h, wq_i, nullptr, nullptr, q, M_, D_, D_);
    gemm_kernel<0><<<gridD, 256, 0, stream>>>(h, wk_i, nullptr, nullptr, k, M_, D_, D_);
    gemm_kernel<0><<<gridD, 256, 0, stream>>>(h, wv_i, nullptr, nullptr, v, M_, D_, D_);
    attn_kernel<<<dim3(L_/32, B_*H_), 256, 0, stream>>>(q, k, v, t0);
    gemm_kernel<1><<<gridD, 256, 0, stream>>>(t0, wo_i, bo + i*D_, nullptr, q, M_, D_, D_);
    add_ln_kernel<<<M_, 256, 0, stream>>>(h, q, g1 + i*D_, b1 + i*D_, h);
    gemm_kernel<2><<<gridF, 256, 0, stream>>>(h, fw1 + (size_t)i*D_*FF_, fb1 + i*FF_, nullptr, fh, M_, FF_, D_);
    gemm_kernel<1><<<gridD, 256, 0, stream>>>(fh, fw2 + (size_t)i*FF_*D_, fb2 + i*D_, nullptr, t0, M_, D_, FF_);
    add_ln_kernel<<<M_, 256, 0, stream>>>(h, t0, g2 + i*D_, b2 + i*D_, (i == NL_-1) ? out : h);
  }
}

// Round 2
// 1242.371 us; speedup vs baseline: 5.7824x; 5.7824x over previous
//
#include <hip/hip_runtime.h>
#include <math.h>

typedef unsigned short u16;
typedef unsigned int   u32;
typedef __bf16 bf16_t;
typedef bf16_t bf16x8 __attribute__((ext_vector_type(8)));
typedef float  f32x4  __attribute__((ext_vector_type(4)));
typedef u16    u16x8  __attribute__((ext_vector_type(8)));

#define B_   8
#define L_   1024
#define DIN_ 32
#define D_   512
#define H_   8
#define NL_  6
#define FF_  64
#define M_   (B_*L_)    // 8192
#define DD_  (D_*D_)    // 262144

#define PE_COEF (-0.017988946039015984f)   // -ln(10000)/512

__device__ __forceinline__ u16 f2bf(float f) {
  u32 u = __builtin_bit_cast(u32, f);
  u32 r = (u + 0x7FFFu + ((u >> 16) & 1u)) >> 16;
  return (u16)r;
}

#define GLOAD_LDS16(gp, lp) \
  __builtin_amdgcn_global_load_lds((const __attribute__((address_space(1))) u32*)(gp), \
                                   (__attribute__((address_space(3))) u32*)(lp), 16, 0, 0)

// ---------------- block reduce (256 threads = 4 waves) ----------------
__device__ __forceinline__ float block_reduce_sum(float v, float* smem4) {
  #pragma unroll
  for (int off = 32; off > 0; off >>= 1) v += __shfl_down(v, off, 64);
  int wid = threadIdx.x >> 6;
  __syncthreads();
  if ((threadIdx.x & 63) == 0) smem4[wid] = v;
  __syncthreads();
  return smem4[0] + smem4[1] + smem4[2] + smem4[3];
}

// ---------------- weight transpose + f32->bf16:  W[K][N] -> Wt[N][K] ----------------
__global__ __launch_bounds__(256) void transpose_k(const float* __restrict__ W, u16* __restrict__ Wt,
                                                   int K, int N, size_t in_zs, size_t out_zs) {
  __shared__ float tile[32][33];
  size_t mi = (size_t)blockIdx.z * in_zs;
  size_t mo = (size_t)blockIdx.z * out_zs;
  int k0 = blockIdx.y * 32, n0 = blockIdx.x * 32;
  int tx = threadIdx.x & 31, ty = threadIdx.x >> 5;   // ty 0..7
  #pragma unroll
  for (int i = 0; i < 4; ++i)
    tile[ty + i*8][tx] = W[mi + (size_t)(k0 + ty + i*8)*N + n0 + tx];
  __syncthreads();
  #pragma unroll
  for (int i = 0; i < 4; ++i)
    Wt[mo + (size_t)(n0 + ty + i*8)*K + k0 + tx] = f2bf(tile[tx][ty + i*8]);
}

// ---------------- embedding MLP stage 1 + LayerNorm (bf16 out) ----------------
__global__ __launch_bounds__(256) void emb1_ln_kernel(const float* __restrict__ x, const float* __restrict__ W1,
                               const float* __restrict__ b1, const float* __restrict__ g,
                               const float* __restrict__ beta, u16* __restrict__ outb) {
  __shared__ float xs[DIN_];
  __shared__ float red[4];
  int m = blockIdx.x;
  int tid = threadIdx.x;
  if (tid < DIN_) xs[tid] = x[m*DIN_ + tid];
  __syncthreads();
  float v[2];
  #pragma unroll
  for (int r = 0; r < 2; ++r) {
    int n = tid + r*256;
    float acc = b1[n];
    #pragma unroll
    for (int k = 0; k < DIN_; ++k) acc += xs[k] * W1[k*D_ + n];
    v[r] = fmaxf(acc, 0.f);
  }
  float mean = block_reduce_sum(v[0] + v[1], red) * (1.f/D_);
  float d0 = v[0] - mean, d1 = v[1] - mean;
  float var = block_reduce_sum(d0*d0 + d1*d1, red) * (1.f/D_);
  float rstd = rsqrtf(var + 1e-5f);
  outb[(size_t)m*D_ + tid]       = f2bf(d0*rstd*g[tid]       + beta[tid]);
  outb[(size_t)m*D_ + tid + 256] = f2bf(d1*rstd*g[tid + 256] + beta[tid + 256]);
}

// ---------------- residual add + LayerNorm (f32 + bf16 out) ----------------
__global__ __launch_bounds__(256) void add_ln_kernel(const float* __restrict__ hin, const float* __restrict__ res,
                              const float* __restrict__ g, const float* __restrict__ b,
                              float* __restrict__ outf, u16* __restrict__ outb) {
  __shared__ float red[4];
  int m = blockIdx.x;
  int tid = threadIdx.x;
  float v0 = hin[(size_t)m*D_ + tid]       + res[(size_t)m*D_ + tid];
  float v1 = hin[(size_t)m*D_ + tid + 256] + res[(size_t)m*D_ + tid + 256];
  float mean = block_reduce_sum(v0 + v1, red) * (1.f/D_);
  float d0 = v0 - mean, d1 = v1 - mean;
  float var = block_reduce_sum(d0*d0 + d1*d1, red) * (1.f/D_);
  float rstd = rsqrtf(var + 1e-5f);
  float o0 = d0*rstd*g[tid]       + b[tid];
  float o1 = d1*rstd*g[tid + 256] + b[tid + 256];
  outf[(size_t)m*D_ + tid]       = o0;
  outf[(size_t)m*D_ + tid + 256] = o1;
  outb[(size_t)m*D_ + tid]       = f2bf(o0);
  outb[(size_t)m*D_ + tid + 256] = f2bf(o1);
}

// ---------------- bf16 MFMA GEMM:  C[M,N] = A[M,K] @ Bt[N,K]^T ----------------
// EPI bits: 1=+bias, 2=relu, 4=+positional-encoding.  WF: write f32 Cf, WB: write bf16 Cb.
template<int BM, int BN, int EPI, bool WF, bool WB>
__global__ __launch_bounds__(256) void mgemm(const u16* __restrict__ A, const u16* __restrict__ Bt,
                            const float* __restrict__ bias, const float* __restrict__ extra,
                            float* __restrict__ Cf, u16* __restrict__ Cb,
                            int M, int N, int K) {
  __shared__ __align__(16) u16 As[BM*32];
  __shared__ __align__(16) u16 Bs[BN*32];
  const int WR = BM/2, WC = BN/2, MR = WR/16, NR = WC/16;
  int bm = blockIdx.y * BM, bn = blockIdx.x * BN;
  int tid = threadIdx.x, w = tid >> 6, l = tid & 63;
  int wr = w >> 1, wc = w & 1;
  int lq = l & 15, lg = l >> 4;
  f32x4 acc[MR][NR];
  #pragma unroll
  for (int m = 0; m < MR; ++m)
    #pragma unroll
    for (int n = 0; n < NR; ++n) acc[m][n] = f32x4{0.f,0.f,0.f,0.f};

  for (int k0 = 0; k0 < K; k0 += 32) {
    #pragma unroll
    for (int i = 0; i < BM/64; ++i) {
      int row = i*64 + w*16 + (l >> 2);
      const u16* gp = A + (size_t)(bm + row)*K + k0 + (l & 3)*8;
      GLOAD_LDS16(gp, As + i*2048 + w*512);
    }
    #pragma unroll
    for (int i = 0; i < BN/64; ++i) {
      int row = i*64 + w*16 + (l >> 2);
      const u16* gp = Bt + (size_t)(bn + row)*K + k0 + (l & 3)*8;
      GLOAD_LDS16(gp, Bs + i*2048 + w*512);
    }
    __syncthreads();
    bf16x8 af[MR], bfr[NR];
    #pragma unroll
    for (int m = 0; m < MR; ++m)
      af[m] = *(const bf16x8*)&As[(wr*WR + m*16 + lq)*32 + lg*8];
    #pragma unroll
    for (int n = 0; n < NR; ++n)
      bfr[n] = *(const bf16x8*)&Bs[(wc*WC + n*16 + lq)*32 + lg*8];
    #pragma unroll
    for (int m = 0; m < MR; ++m)
      #pragma unroll
      for (int n = 0; n < NR; ++n)
        acc[m][n] = __builtin_amdgcn_mfma_f32_16x16x32_bf16(af[m], bfr[n], acc[m][n], 0, 0, 0);
    __syncthreads();
  }

  #pragma unroll
  for (int m = 0; m < MR; ++m) {
    #pragma unroll
    for (int n = 0; n < NR; ++n) {
      #pragma unroll
      for (int r = 0; r < 4; ++r) {
        int row = bm + wr*WR + m*16 + lg*4 + r;
        int col = bn + wc*WC + n*16 + lq;
        float v = acc[m][n][r];
        if (EPI & 1) v += bias[col];
        if (EPI & 2) v = fmaxf(v, 0.f);
        if (EPI & 4) {
          float fr  = __expf((float)(col & ~1) * PE_COEF);
          float arg = extra[row] * fr;
          v += (col & 1) ? cosf(arg) : sinf(arg);
        }
        if (WF) Cf[(size_t)row*N + col] = v;
        if (WB) Cb[(size_t)row*N + col] = f2bf(v);
      }
    }
  }
}

// ---------------- MFMA causal flash attention ----------------
// Q/K/V are column slices of qkvb [M][1536]: base pointers, row stride 1536, head cols col0..col0+63.
// Output ob [M][512] bf16. 4 waves x 16 q-rows per block (64-row q tile), KV tiles of 32.
#define QS_ 1536
__global__ __launch_bounds__(256) void attn_kernel(const u16* __restrict__ Q, const u16* __restrict__ Kp,
                                                   const u16* __restrict__ V, u16* __restrict__ O) {
  __shared__ __align__(16) u16 Ks[32*72];     // [kv][d] stride 72
  __shared__ __align__(16) u16 Vt[64*40];     // [d][kv] stride 40
  __shared__ __align__(16) u16 Ps[4][16*40];  // per-wave [q][kv] stride 40
  int qt = blockIdx.x, bh = blockIdx.y;
  int b = bh >> 3, hh = bh & 7;
  int rowbase = b * L_, col0 = hh * 64;
  int tid = threadIdx.x, w = tid >> 6, l = tid & 63;
  int lq = l & 15, lg = l >> 4;

  // Q fragments (registers, whole loop)
  int qrow = rowbase + qt*64 + w*16 + lq;
  bf16x8 qa0 = *(const bf16x8*)&Q[(size_t)qrow*QS_ + col0 + lg*8];
  bf16x8 qa1 = *(const bf16x8*)&Q[(size_t)qrow*QS_ + col0 + 32 + lg*8];

  float m_st[4], l_st[4];
  f32x4 o[4];
  #pragma unroll
  for (int r = 0; r < 4; ++r) { m_st[r] = -1e30f; l_st[r] = 0.f; }
  #pragma unroll
  for (int n = 0; n < 4; ++n) o[n] = f32x4{0.f,0.f,0.f,0.f};
  int qg[4];
  #pragma unroll
  for (int r = 0; r < 4; ++r) qg[r] = qt*64 + w*16 + lg*4 + r;

  int srow = tid >> 3, sseg = tid & 7;         // K staging
  int vd = tid & 63, vkv = (tid >> 6) * 8;     // V staging
  int nkt = 2*qt + 2;
  int wmax = qt*64 + w*16 + 15;

  for (int kt = 0; kt < nkt; ++kt) {
    __syncthreads();  // previous-iter readers done
    *(u16x8*)&Ks[srow*72 + sseg*8] =
        *(const u16x8*)&Kp[(size_t)(rowbase + kt*32 + srow)*QS_ + col0 + sseg*8];
    u16x8 vv;
    #pragma unroll
    for (int i = 0; i < 8; ++i)
      vv[i] = V[(size_t)(rowbase + kt*32 + vkv + i)*QS_ + col0 + vd];
    *(u16x8*)&Vt[vd*40 + vkv] = vv;
    __syncthreads();

    if (kt*32 <= wmax) {
      // S = Q K^T  (two kv-halves, two d-steps each)
      f32x4 s[2];
      #pragma unroll
      for (int f = 0; f < 2; ++f) {
        bf16x8 k0 = *(const bf16x8*)&Ks[(f*16 + lq)*72 + lg*8];
        bf16x8 k1 = *(const bf16x8*)&Ks[(f*16 + lq)*72 + 32 + lg*8];
        f32x4 z = f32x4{0.f,0.f,0.f,0.f};
        z = __builtin_amdgcn_mfma_f32_16x16x32_bf16(qa0, k0, z, 0, 0, 0);
        z = __builtin_amdgcn_mfma_f32_16x16x32_bf16(qa1, k1, z, 0, 0, 0);
        s[f] = z;
      }
      // scale + causal mask
      #pragma unroll
      for (int f = 0; f < 2; ++f) {
        int kvg = kt*32 + f*16 + lq;
        #pragma unroll
        for (int r = 0; r < 4; ++r) {
          float sv = s[f][r] * 0.125f;
          s[f][r] = (kvg > qg[r]) ? -1e30f : sv;
        }
      }
      // online softmax per row r
      #pragma unroll
      for (int r = 0; r < 4; ++r) {
        float v = fmaxf(s[0][r], s[1][r]);
        v = fmaxf(v, __shfl_xor(v, 1));
        v = fmaxf(v, __shfl_xor(v, 2));
        v = fmaxf(v, __shfl_xor(v, 4));
        v = fmaxf(v, __shfl_xor(v, 8));
        float mn = fmaxf(m_st[r], v);
        float corr = __expf(m_st[r] - mn);
        float p0 = __expf(s[0][r] - mn);
        float p1 = __expf(s[1][r] - mn);
        float rs = p0 + p1;
        rs += __shfl_xor(rs, 1);
        rs += __shfl_xor(rs, 2);
        rs += __shfl_xor(rs, 4);
        rs += __shfl_xor(rs, 8);
        l_st[r] = l_st[r]*corr + rs;
        m_st[r] = mn;
        #pragma unroll
        for (int n = 0; n < 4; ++n) o[n][r] *= corr;
        Ps[w][(lg*4 + r)*40 + lq]      = f2bf(p0);
        Ps[w][(lg*4 + r)*40 + lq + 16] = f2bf(p1);
      }
      // PV
      bf16x8 pa = *(const bf16x8*)&Ps[w][lq*40 + lg*8];
      #pragma unroll
      for (int n = 0; n < 4; ++n) {
        bf16x8 vf = *(const bf16x8*)&Vt[(n*16 + lq)*40 + lg*8];
        o[n] = __builtin_amdgcn_mfma_f32_16x16x32_bf16(pa, vf, o[n], 0, 0, 0);
      }
    }
  }

  #pragma unroll
  for (int r = 0; r < 4; ++r) {
    float inv = 1.f / l_st[r];
    #pragma unroll
    for (int n = 0; n < 4; ++n)
      O[(size_t)(rowbase + qt*64 + w*16 + lg*4 + r)*D_ + col0 + n*16 + lq] = f2bf(o[n][r] * inv);
  }
}

// ---------------- host ----------------
extern "C" void kernel_launch(void* const* d_in, const int* in_sizes, int n_in,
                              void* d_out, int out_size, void* d_ws, size_t ws_size,
                              hipStream_t stream) {
  (void)in_sizes; (void)n_in; (void)out_size; (void)ws_size;
  const float* x      = (const float*)d_in[0];
  const float* obs    = (const float*)d_in[2];
  const float* emb_w1 = (const float*)d_in[3];
  const float* emb_b1 = (const float*)d_in[4];
  const float* emb_g  = (const float*)d_in[5];
  const float* emb_be = (const float*)d_in[6];
  const float* emb_w2 = (const float*)d_in[7];
  const float* emb_b2 = (const float*)d_in[8];
  const float* wq  = (const float*)d_in[9];
  const float* wk  = (const float*)d_in[10];
  const float* wv  = (const float*)d_in[11];
  const float* wo  = (const float*)d_in[12];
  const float* bo  = (const float*)d_in[13];
  const float* fw1 = (const float*)d_in[14];
  const float* fb1 = (const float*)d_in[15];
  const float* fw2 = (const float*)d_in[16];
  const float* fb2 = (const float*)d_in[17];
  const float* g1  = (const float*)d_in[18];
  const float* b1  = (const float*)d_in[19];
  const float* g2  = (const float*)d_in[20];
  const float* b2  = (const float*)d_in[21];
  float* out = (float*)d_out;

  float* hf  = (float*)d_ws;                  // [M,D] f32 residual
  float* of  = hf + (size_t)M_*D_;            // [M,D] f32 branch out
  u16* hb    = (u16*)(of + (size_t)M_*D_);    // [M,D] bf16 copy of hf
  u16* qkvb  = hb + (size_t)M_*D_;            // [M,3D] bf16 fused qkv
  u16* ob    = qkvb + (size_t)M_*3*D_;        // [M,D] bf16 (emb1 out / attn out)
  u16* fhb   = ob + (size_t)M_*D_;            // [M,FF] bf16
  u16* qkvt  = fhb + (size_t)M_*FF_;          // [NL][3][D][D] bf16 (W^T)
  u16* wot   = qkvt + (size_t)18*DD_;         // [NL][D][D]
  u16* ew2t  = wot + (size_t)6*DD_;           // [D][D]
  u16* fw1t  = ew2t + (size_t)DD_;            // [NL][FF][D]
  u16* fw2t  = fw1t + (size_t)6*D_*FF_;       // [NL][D][FF]

  // weight transpose+convert
  transpose_k<<<dim3(16,16,6), 256, 0, stream>>>(wq, qkvt,          512, 512, DD_, 3*(size_t)DD_);
  transpose_k<<<dim3(16,16,6), 256, 0, stream>>>(wk, qkvt + DD_,    512, 512, DD_, 3*(size_t)DD_);
  transpose_k<<<dim3(16,16,6), 256, 0, stream>>>(wv, qkvt + 2*DD_,  512, 512, DD_, 3*(size_t)DD_);
  transpose_k<<<dim3(16,16,6), 256, 0, stream>>>(wo, wot,           512, 512, DD_, DD_);
  transpose_k<<<dim3(16,16,1), 256, 0, stream>>>(emb_w2, ew2t,      512, 512, DD_, DD_);
  transpose_k<<<dim3(2,16,6),  256, 0, stream>>>(fw1, fw1t,         512,  64, (size_t)D_*FF_, (size_t)D_*FF_);
  transpose_k<<<dim3(16,2,6),  256, 0, stream>>>(fw2, fw2t,          64, 512, (size_t)D_*FF_, (size_t)D_*FF_);

  emb1_ln_kernel<<<M_, 256, 0, stream>>>(x, emb_w1, emb_b1, emb_g, emb_be, ob);
  // h = ob @ emb_w2 + b2 + PE  -> hf (f32) + hb (bf16)
  mgemm<128,128,5,true,true><<<dim3(4,64), 256, 0, stream>>>(ob, ew2t, emb_b2, obs, hf, hb, M_, D_, D_);

  for (int i = 0; i < NL_; ++i) {
    // fused QKV projection: [M,1536]
    mgemm<128,128,0,false,true><<<dim3(12,64), 256, 0, stream>>>(hb, qkvt + (size_t)i*3*DD_,
        nullptr, nullptr, nullptr, qkvb, M_, 3*D_, D_);
    attn_kernel<<<dim3(L_/64, B_*H_), 256, 0, stream>>>(qkvb, qkvb + D_, qkvb + 2*D_, ob);
    mgemm<128,128,1,true,false><<<dim3(4,64), 256, 0, stream>>>(ob, wot + (size_t)i*DD_,
        bo + i*D_, nullptr, of, nullptr, M_, D_, D_);
    add_ln_kernel<<<M_, 256, 0, stream>>>(hf, of, g1 + i*D_, b1 + i*D_, hf, hb);
    mgemm<64,64,3,false,true><<<dim3(1,128), 256, 0, stream>>>(hb, fw1t + (size_t)i*D_*FF_,
        fb1 + i*FF_, nullptr, nullptr, fhb, M_, FF_, D_);
    mgemm<128,128,1,true,false><<<dim3(4,64), 256, 0, stream>>>(fhb, fw2t + (size_t)i*D_*FF_,
        fb2 + i*D_, nullptr, of, nullptr, M_, D_, FF_);
    add_ln_kernel<<<M_, 256, 0, stream>>>(hf, of, g2 + i*D_, b2 + i*D_,
        (i == NL_-1) ? out : hf, hb);
  }
}

// Round 3
// 945.151 us; speedup vs baseline: 7.6008x; 1.3145x over previous
//
#include <hip/hip_runtime.h>
#include <math.h>

typedef unsigned short u16;
typedef unsigned int   u32;
typedef __bf16 bf16_t;
typedef bf16_t bf16x8 __attribute__((ext_vector_type(8)));
typedef float  f32x4  __attribute__((ext_vector_type(4)));
typedef u16    u16x8  __attribute__((ext_vector_type(8)));

#define B_   8
#define L_   1024
#define DIN_ 32
#define D_   512
#define H_   8
#define NL_  6
#define FF_  64
#define M_   (B_*L_)    // 8192
#define DD_  (D_*D_)    // 262144

#define PE_COEF (-0.017988946039015984f)   // -ln(10000)/512
#define SC2     (0.18033688011112042f)     // 0.125 * log2(e)

__device__ __forceinline__ u16 f2bf(float f) {
  u32 u = __builtin_bit_cast(u32, f);
  u32 r = (u + 0x7FFFu + ((u >> 16) & 1u)) >> 16;
  return (u16)r;
}
__device__ __forceinline__ u16 f2bf_fast(float f) {   // positive values (P in [0,1])
  u32 u = __builtin_bit_cast(u32, f);
  return (u16)((u + 0x8000u) >> 16);
}
__device__ __forceinline__ float bf2f(u16 v) {
  u32 u = ((u32)v) << 16;
  return __builtin_bit_cast(float, u);
}

#define GLOAD_LDS16(gp, lp) \
  __builtin_amdgcn_global_load_lds((const __attribute__((address_space(1))) u32*)(gp), \
                                   (__attribute__((address_space(3))) u32*)(lp), 16, 0, 0)

// ---------------- block reduce (256 threads = 4 waves) ----------------
__device__ __forceinline__ float block_reduce_sum(float v, float* smem4) {
  #pragma unroll
  for (int off = 32; off > 0; off >>= 1) v += __shfl_down(v, off, 64);
  int wid = threadIdx.x >> 6;
  __syncthreads();
  if ((threadIdx.x & 63) == 0) smem4[wid] = v;
  __syncthreads();
  return smem4[0] + smem4[1] + smem4[2] + smem4[3];
}

// ---------------- weight transpose + f32->bf16:  W[K][N] -> Wt[N][K] ----------------
__global__ __launch_bounds__(256) void transpose_k(const float* __restrict__ W, u16* __restrict__ Wt,
                                                   int K, int N, size_t in_zs, size_t out_zs) {
  __shared__ float tile[32][33];
  size_t mi = (size_t)blockIdx.z * in_zs;
  size_t mo = (size_t)blockIdx.z * out_zs;
  int k0 = blockIdx.y * 32, n0 = blockIdx.x * 32;
  int tx = threadIdx.x & 31, ty = threadIdx.x >> 5;   // ty 0..7
  #pragma unroll
  for (int i = 0; i < 4; ++i)
    tile[ty + i*8][tx] = W[mi + (size_t)(k0 + ty + i*8)*N + n0 + tx];
  __syncthreads();
  #pragma unroll
  for (int i = 0; i < 4; ++i)
    Wt[mo + (size_t)(n0 + ty + i*8)*K + k0 + tx] = f2bf(tile[tx][ty + i*8]);
}

// ---------------- embedding MLP stage 1 + LayerNorm (bf16 out) ----------------
__global__ __launch_bounds__(256) void emb1_ln_kernel(const float* __restrict__ x, const float* __restrict__ W1,
                               const float* __restrict__ b1, const float* __restrict__ g,
                               const float* __restrict__ beta, u16* __restrict__ outb) {
  __shared__ float xs[DIN_];
  __shared__ float red[4];
  int m = blockIdx.x;
  int tid = threadIdx.x;
  if (tid < DIN_) xs[tid] = x[m*DIN_ + tid];
  __syncthreads();
  float v[2];
  #pragma unroll
  for (int r = 0; r < 2; ++r) {
    int n = tid + r*256;
    float acc = b1[n];
    #pragma unroll
    for (int k = 0; k < DIN_; ++k) acc += xs[k] * W1[k*D_ + n];
    v[r] = fmaxf(acc, 0.f);
  }
  float mean = block_reduce_sum(v[0] + v[1], red) * (1.f/D_);
  float d0 = v[0] - mean, d1 = v[1] - mean;
  float var = block_reduce_sum(d0*d0 + d1*d1, red) * (1.f/D_);
  float rstd = rsqrtf(var + 1e-5f);
  outb[(size_t)m*D_ + tid]       = f2bf(d0*rstd*g[tid]       + beta[tid]);
  outb[(size_t)m*D_ + tid + 256] = f2bf(d1*rstd*g[tid + 256] + beta[tid + 256]);
}

// ---------------- residual add + LayerNorm (res branch is bf16) ----------------
__global__ __launch_bounds__(256) void add_ln_kernel(const float* __restrict__ hin, const u16* __restrict__ res,
                              const float* __restrict__ g, const float* __restrict__ b,
                              float* __restrict__ outf, u16* __restrict__ outb) {
  __shared__ float red[4];
  int m = blockIdx.x;
  int tid = threadIdx.x;
  float v0 = hin[(size_t)m*D_ + tid]       + bf2f(res[(size_t)m*D_ + tid]);
  float v1 = hin[(size_t)m*D_ + tid + 256] + bf2f(res[(size_t)m*D_ + tid + 256]);
  float mean = block_reduce_sum(v0 + v1, red) * (1.f/D_);
  float d0 = v0 - mean, d1 = v1 - mean;
  float var = block_reduce_sum(d0*d0 + d1*d1, red) * (1.f/D_);
  float rstd = rsqrtf(var + 1e-5f);
  float o0 = d0*rstd*g[tid]       + b[tid];
  float o1 = d1*rstd*g[tid + 256] + b[tid + 256];
  outf[(size_t)m*D_ + tid]       = o0;
  outf[(size_t)m*D_ + tid + 256] = o1;
  outb[(size_t)m*D_ + tid]       = f2bf(o0);
  outb[(size_t)m*D_ + tid + 256] = f2bf(o1);
}

// ---------------- bf16 MFMA GEMM:  C[M,N] = A[M,K] @ Bt[N,K]^T ----------------
// EPI bits: 1=+bias, 2=relu, 4=+positional-encoding.  WF: write f32 Cf, WB: write bf16 Cb.
template<int BM, int BN, int EPI, bool WF, bool WB>
__global__ __launch_bounds__(256) void mgemm(const u16* __restrict__ A, const u16* __restrict__ Bt,
                            const float* __restrict__ bias, const float* __restrict__ extra,
                            float* __restrict__ Cf, u16* __restrict__ Cb,
                            int M, int N, int K) {
  __shared__ __align__(16) u16 As[BM*32];
  __shared__ __align__(16) u16 Bs[BN*32];
  const int WR = BM/2, WC = BN/2, MR = WR/16, NR = WC/16;
  int bm = blockIdx.y * BM, bn = blockIdx.x * BN;
  int tid = threadIdx.x, w = tid >> 6, l = tid & 63;
  int wr = w >> 1, wc = w & 1;
  int lq = l & 15, lg = l >> 4;
  f32x4 acc[MR][NR];
  #pragma unroll
  for (int m = 0; m < MR; ++m)
    #pragma unroll
    for (int n = 0; n < NR; ++n) acc[m][n] = f32x4{0.f,0.f,0.f,0.f};

  for (int k0 = 0; k0 < K; k0 += 32) {
    #pragma unroll
    for (int i = 0; i < BM/64; ++i) {
      int row = i*64 + w*16 + (l >> 2);
      const u16* gp = A + (size_t)(bm + row)*K + k0 + (l & 3)*8;
      GLOAD_LDS16(gp, As + i*2048 + w*512);
    }
    #pragma unroll
    for (int i = 0; i < BN/64; ++i) {
      int row = i*64 + w*16 + (l >> 2);
      const u16* gp = Bt + (size_t)(bn + row)*K + k0 + (l & 3)*8;
      GLOAD_LDS16(gp, Bs + i*2048 + w*512);
    }
    __syncthreads();
    bf16x8 af[MR], bfr[NR];
    #pragma unroll
    for (int m = 0; m < MR; ++m)
      af[m] = *(const bf16x8*)&As[(wr*WR + m*16 + lq)*32 + lg*8];
    #pragma unroll
    for (int n = 0; n < NR; ++n)
      bfr[n] = *(const bf16x8*)&Bs[(wc*WC + n*16 + lq)*32 + lg*8];
    #pragma unroll
    for (int m = 0; m < MR; ++m)
      #pragma unroll
      for (int n = 0; n < NR; ++n)
        acc[m][n] = __builtin_amdgcn_mfma_f32_16x16x32_bf16(af[m], bfr[n], acc[m][n], 0, 0, 0);
    __syncthreads();
  }

  #pragma unroll
  for (int m = 0; m < MR; ++m) {
    #pragma unroll
    for (int n = 0; n < NR; ++n) {
      #pragma unroll
      for (int r = 0; r < 4; ++r) {
        int row = bm + wr*WR + m*16 + lg*4 + r;
        int col = bn + wc*WC + n*16 + lq;
        float v = acc[m][n][r];
        if (EPI & 1) v += bias[col];
        if (EPI & 2) v = fmaxf(v, 0.f);
        if (EPI & 4) {
          float fr  = __expf((float)(col & ~1) * PE_COEF);
          float arg = extra[row] * fr;
          v += (col & 1) ? cosf(arg) : sinf(arg);
        }
        if (WF) Cf[(size_t)row*N + col] = v;
        if (WB) Cb[(size_t)row*N + col] = f2bf(v);
      }
    }
  }
}

// ---------------- MFMA causal flash attention, KVBLK=64, paired q-tiles ----------------
// Q/K/V are column slices of qkvb [M][1536]. Output ob [M][512] bf16.
// Block = 4 waves; wave w owns 16 q rows. Block processes q-tiles {pair, 15-pair}
// (64 rows each) -> uniform 17 kv-tile-steps per block.
#define QS_ 1536
__global__ __launch_bounds__(256) void attn_kernel(const u16* __restrict__ Q, const u16* __restrict__ Kp,
                                                   const u16* __restrict__ V, u16* __restrict__ O) {
  __shared__ __align__(16) u16 Ks[64*72];     // [kv][d]  stride 72
  __shared__ __align__(16) u16 Vt[64*72];     // [d][kv]  stride 72
  __shared__ __align__(16) u16 Ps[4][16*72];  // per-wave [q][kv] stride 72
  int pair = blockIdx.x, bh = blockIdx.y;
  int b = bh >> 3, hh = bh & 7;
  int rowbase = b * L_, col0 = hh * 64;
  int tid = threadIdx.x, w = tid >> 6, l = tid & 63;
  int lq = l & 15, lg = l >> 4;

  int krow = tid >> 3, kseg = tid & 7;        // K staging
  int vg = tid >> 5, vd2 = (tid & 31) * 2;    // V staging (transpose via u32)

  #pragma unroll 1
  for (int half = 0; half < 2; ++half) {
    int qt = half ? (15 - pair) : pair;
    int qrow = rowbase + qt*64 + w*16 + lq;
    bf16x8 qa0 = *(const bf16x8*)&Q[(size_t)qrow*QS_ + col0 + lg*8];
    bf16x8 qa1 = *(const bf16x8*)&Q[(size_t)qrow*QS_ + col0 + 32 + lg*8];
    float m_st[4], l_st[4];
    f32x4 o[4];
    #pragma unroll
    for (int r = 0; r < 4; ++r) { m_st[r] = -1e30f; l_st[r] = 0.f; }
    #pragma unroll
    for (int n = 0; n < 4; ++n) o[n] = f32x4{0.f,0.f,0.f,0.f};

    #pragma unroll 1
    for (int kt = 0; kt <= qt; ++kt) {
      __syncthreads();            // previous tile/half readers done
      #pragma unroll
      for (int i = 0; i < 2; ++i) {
        int row = krow + i*32;
        *(u16x8*)&Ks[row*72 + kseg*8] =
            *(const u16x8*)&Kp[(size_t)(rowbase + kt*64 + row)*QS_ + col0 + kseg*8];
      }
      u32 c[8];
      #pragma unroll
      for (int i = 0; i < 8; ++i)
        c[i] = *(const u32*)&V[(size_t)(rowbase + kt*64 + vg*8 + i)*QS_ + col0 + vd2];
      u16x8 vlo, vhi;
      #pragma unroll
      for (int i = 0; i < 8; ++i) { vlo[i] = (u16)(c[i] & 0xffffu); vhi[i] = (u16)(c[i] >> 16); }
      *(u16x8*)&Vt[vd2*72 + vg*8]     = vlo;
      *(u16x8*)&Vt[(vd2+1)*72 + vg*8] = vhi;
      __syncthreads();

      // S = Q K^T, scaled into log2 domain
      f32x4 t[4];
      #pragma unroll
      for (int f = 0; f < 4; ++f) {
        bf16x8 k0 = *(const bf16x8*)&Ks[(f*16 + lq)*72 + lg*8];
        bf16x8 k1 = *(const bf16x8*)&Ks[(f*16 + lq)*72 + 32 + lg*8];
        f32x4 z = f32x4{0.f,0.f,0.f,0.f};
        z = __builtin_amdgcn_mfma_f32_16x16x32_bf16(qa0, k0, z, 0, 0, 0);
        z = __builtin_amdgcn_mfma_f32_16x16x32_bf16(qa1, k1, z, 0, 0, 0);
        #pragma unroll
        for (int r = 0; r < 4; ++r) t[f][r] = z[r] * SC2;
      }
      if (kt == qt) {             // diagonal tile: causal mask
        #pragma unroll
        for (int f = 0; f < 4; ++f) {
          int kvg = f*16 + lq;
          #pragma unroll
          for (int r = 0; r < 4; ++r)
            if (kvg > w*16 + lg*4 + r) t[f][r] = -1e30f;
        }
      }
      // online softmax (exp2 domain), 4 rows per lane-group
      #pragma unroll
      for (int r = 0; r < 4; ++r) {
        float tm = fmaxf(fmaxf(t[0][r], t[1][r]), fmaxf(t[2][r], t[3][r]));
        tm = fmaxf(tm, __shfl_xor(tm, 1));
        tm = fmaxf(tm, __shfl_xor(tm, 2));
        tm = fmaxf(tm, __shfl_xor(tm, 4));
        tm = fmaxf(tm, __shfl_xor(tm, 8));
        float mn = fmaxf(m_st[r], tm);
        float corr = __builtin_amdgcn_exp2f(m_st[r] - mn);
        float p0 = __builtin_amdgcn_exp2f(t[0][r] - mn);
        float p1 = __builtin_amdgcn_exp2f(t[1][r] - mn);
        float p2 = __builtin_amdgcn_exp2f(t[2][r] - mn);
        float p3 = __builtin_amdgcn_exp2f(t[3][r] - mn);
        float rs = (p0 + p1) + (p2 + p3);
        rs += __shfl_xor(rs, 1);
        rs += __shfl_xor(rs, 2);
        rs += __shfl_xor(rs, 4);
        rs += __shfl_xor(rs, 8);
        l_st[r] = l_st[r]*corr + rs;
        m_st[r] = mn;
        #pragma unroll
        for (int n = 0; n < 4; ++n) o[n][r] *= corr;
        int prow = (lg*4 + r)*72;
        Ps[w][prow + lq]      = f2bf_fast(p0);
        Ps[w][prow + 16 + lq] = f2bf_fast(p1);
        Ps[w][prow + 32 + lq] = f2bf_fast(p2);
        Ps[w][prow + 48 + lq] = f2bf_fast(p3);
      }
      // PV
      bf16x8 pa0 = *(const bf16x8*)&Ps[w][lq*72 + lg*8];
      bf16x8 pa1 = *(const bf16x8*)&Ps[w][lq*72 + 32 + lg*8];
      #pragma unroll
      for (int n = 0; n < 4; ++n) {
        bf16x8 v0 = *(const bf16x8*)&Vt[(n*16 + lq)*72 + lg*8];
        bf16x8 v1 = *(const bf16x8*)&Vt[(n*16 + lq)*72 + 32 + lg*8];
        o[n] = __builtin_amdgcn_mfma_f32_16x16x32_bf16(pa0, v0, o[n], 0, 0, 0);
        o[n] = __builtin_amdgcn_mfma_f32_16x16x32_bf16(pa1, v1, o[n], 0, 0, 0);
      }
    }
    #pragma unroll
    for (int r = 0; r < 4; ++r) {
      float inv = 1.f / l_st[r];
      #pragma unroll
      for (int n = 0; n < 4; ++n)
        O[(size_t)(rowbase + qt*64 + w*16 + lg*4 + r)*D_ + col0 + n*16 + lq] = f2bf(o[n][r] * inv);
    }
  }
}

// ---------------- host ----------------
extern "C" void kernel_launch(void* const* d_in, const int* in_sizes, int n_in,
                              void* d_out, int out_size, void* d_ws, size_t ws_size,
                              hipStream_t stream) {
  (void)in_sizes; (void)n_in; (void)out_size; (void)ws_size;
  const float* x      = (const float*)d_in[0];
  const float* obs    = (const float*)d_in[2];
  const float* emb_w1 = (const float*)d_in[3];
  const float* emb_b1 = (const float*)d_in[4];
  const float* emb_g  = (const float*)d_in[5];
  const float* emb_be = (const float*)d_in[6];
  const float* emb_w2 = (const float*)d_in[7];
  const float* emb_b2 = (const float*)d_in[8];
  const float* wq  = (const float*)d_in[9];
  const float* wk  = (const float*)d_in[10];
  const float* wv  = (const float*)d_in[11];
  const float* wo  = (const float*)d_in[12];
  const float* bo  = (const float*)d_in[13];
  const float* fw1 = (const float*)d_in[14];
  const float* fb1 = (const float*)d_in[15];
  const float* fw2 = (const float*)d_in[16];
  const float* fb2 = (const float*)d_in[17];
  const float* g1  = (const float*)d_in[18];
  const float* b1  = (const float*)d_in[19];
  const float* g2  = (const float*)d_in[20];
  const float* b2  = (const float*)d_in[21];
  float* out = (float*)d_out;

  float* hf  = (float*)d_ws;                  // [M,D] f32 residual
  u16* hb    = (u16*)(hf + (size_t)M_*D_);    // [M,D] bf16 copy of hf
  u16* qkvb  = hb + (size_t)M_*D_;            // [M,3D] bf16 fused qkv
  u16* ob    = qkvb + (size_t)M_*3*D_;        // [M,D] bf16 (emb1 out / attn out)
  u16* ofb   = ob + (size_t)M_*D_;            // [M,D] bf16 branch out
  u16* fhb   = ofb + (size_t)M_*D_;           // [M,FF] bf16
  u16* qkvt  = fhb + (size_t)M_*FF_;          // [NL][3][D][D] bf16 (W^T)
  u16* wot   = qkvt + (size_t)18*DD_;         // [NL][D][D]
  u16* ew2t  = wot + (size_t)6*DD_;           // [D][D]
  u16* fw1t  = ew2t + (size_t)DD_;            // [NL][FF][D]
  u16* fw2t  = fw1t + (size_t)6*D_*FF_;       // [NL][D][FF]

  // weight transpose+convert
  transpose_k<<<dim3(16,16,6), 256, 0, stream>>>(wq, qkvt,          512, 512, DD_, 3*(size_t)DD_);
  transpose_k<<<dim3(16,16,6), 256, 0, stream>>>(wk, qkvt + DD_,    512, 512, DD_, 3*(size_t)DD_);
  transpose_k<<<dim3(16,16,6), 256, 0, stream>>>(wv, qkvt + 2*DD_,  512, 512, DD_, 3*(size_t)DD_);
  transpose_k<<<dim3(16,16,6), 256, 0, stream>>>(wo, wot,           512, 512, DD_, DD_);
  transpose_k<<<dim3(16,16,1), 256, 0, stream>>>(emb_w2, ew2t,      512, 512, DD_, DD_);
  transpose_k<<<dim3(2,16,6),  256, 0, stream>>>(fw1, fw1t,         512,  64, (size_t)D_*FF_, (size_t)D_*FF_);
  transpose_k<<<dim3(16,2,6),  256, 0, stream>>>(fw2, fw2t,          64, 512, (size_t)D_*FF_, (size_t)D_*FF_);

  emb1_ln_kernel<<<M_, 256, 0, stream>>>(x, emb_w1, emb_b1, emb_g, emb_be, ob);
  // h = ob @ emb_w2 + b2 + PE  -> hf (f32) + hb (bf16)
  mgemm<128,128,5,true,true><<<dim3(4,64), 256, 0, stream>>>(ob, ew2t, emb_b2, obs, hf, hb, M_, D_, D_);

  for (int i = 0; i < NL_; ++i) {
    // fused QKV projection: [M,1536]
    mgemm<128,128,0,false,true><<<dim3(12,64), 256, 0, stream>>>(hb, qkvt + (size_t)i*3*DD_,
        nullptr, nullptr, nullptr, qkvb, M_, 3*D_, D_);
    attn_kernel<<<dim3(8, B_*H_), 256, 0, stream>>>(qkvb, qkvb + D_, qkvb + 2*D_, ob);
    mgemm<128,128,1,false,true><<<dim3(4,64), 256, 0, stream>>>(ob, wot + (size_t)i*DD_,
        bo + i*D_, nullptr, nullptr, ofb, M_, D_, D_);
    add_ln_kernel<<<M_, 256, 0, stream>>>(hf, ofb, g1 + i*D_, b1 + i*D_, hf, hb);
    mgemm<64,64,3,false,true><<<dim3(1,128), 256, 0, stream>>>(hb, fw1t + (size_t)i*D_*FF_,
        fb1 + i*FF_, nullptr, nullptr, fhb, M_, FF_, D_);
    mgemm<128,128,1,false,true><<<dim3(4,64), 256, 0, stream>>>(fhb, fw2t + (size_t)i*D_*FF_,
        fb2 + i*D_, nullptr, nullptr, ofb, M_, D_, FF_);
    add_ln_kernel<<<M_, 256, 0, stream>>>(hf, ofb, g2 + i*D_, b2 + i*D_,
        (i == NL_-1) ? out : hf, hb);
  }
}

// Round 4
// 866.051 us; speedup vs baseline: 8.2950x; 1.0913x over previous
//
#include <hip/hip_runtime.h>
#include <math.h>

typedef unsigned short u16;
typedef unsigned int   u32;
typedef __bf16 bf16_t;
typedef bf16_t bf16x8 __attribute__((ext_vector_type(8)));
typedef float  f32x4  __attribute__((ext_vector_type(4)));
typedef u16    u16x8  __attribute__((ext_vector_type(8)));
typedef u16    u16x4  __attribute__((ext_vector_type(4)));

#define B_   8
#define L_   1024
#define DIN_ 32
#define D_   512
#define H_   8
#define NL_  6
#define FF_  64
#define M_   (B_*L_)    // 8192
#define DD_  (D_*D_)    // 262144

#define PE_COEF (-0.017988946039015984f)   // -ln(10000)/512
#define SC2     (0.18033688011112042f)     // 0.125 * log2(e)

__device__ __forceinline__ u16 f2bf(float f) {
  u32 u = __builtin_bit_cast(u32, f);
  u32 r = (u + 0x7FFFu + ((u >> 16) & 1u)) >> 16;
  return (u16)r;
}
__device__ __forceinline__ u16 f2bf_fast(float f) {   // positive values (P in [0,1])
  u32 u = __builtin_bit_cast(u32, f);
  return (u16)((u + 0x8000u) >> 16);
}
__device__ __forceinline__ float bf2f(u16 v) {
  u32 u = ((u32)v) << 16;
  return __builtin_bit_cast(float, u);
}

#define GLOAD_LDS16(gp, lp) \
  __builtin_amdgcn_global_load_lds((const __attribute__((address_space(1))) u32*)(gp), \
                                   (__attribute__((address_space(3))) u32*)(lp), 16, 0, 0)

// ---------------- block reduce (256 threads = 4 waves) ----------------
__device__ __forceinline__ float block_reduce_sum(float v, float* smem4) {
  #pragma unroll
  for (int off = 32; off > 0; off >>= 1) v += __shfl_down(v, off, 64);
  int wid = threadIdx.x >> 6;
  __syncthreads();
  if ((threadIdx.x & 63) == 0) smem4[wid] = v;
  __syncthreads();
  return smem4[0] + smem4[1] + smem4[2] + smem4[3];
}

// ---------------- weight transpose + f32->bf16:  W[K][N] -> Wt[N][K] ----------------
__global__ __launch_bounds__(256) void transpose_k(const float* __restrict__ W, u16* __restrict__ Wt,
                                                   int K, int N, size_t in_zs, size_t out_zs) {
  __shared__ float tile[32][33];
  size_t mi = (size_t)blockIdx.z * in_zs;
  size_t mo = (size_t)blockIdx.z * out_zs;
  int k0 = blockIdx.y * 32, n0 = blockIdx.x * 32;
  int tx = threadIdx.x & 31, ty = threadIdx.x >> 5;   // ty 0..7
  #pragma unroll
  for (int i = 0; i < 4; ++i)
    tile[ty + i*8][tx] = W[mi + (size_t)(k0 + ty + i*8)*N + n0 + tx];
  __syncthreads();
  #pragma unroll
  for (int i = 0; i < 4; ++i)
    Wt[mo + (size_t)(n0 + ty + i*8)*K + k0 + tx] = f2bf(tile[tx][ty + i*8]);
}

// ---------------- embedding MLP stage 1 + LayerNorm (bf16 out) ----------------
__global__ __launch_bounds__(256) void emb1_ln_kernel(const float* __restrict__ x, const float* __restrict__ W1,
                               const float* __restrict__ b1, const float* __restrict__ g,
                               const float* __restrict__ beta, u16* __restrict__ outb) {
  __shared__ float xs[DIN_];
  __shared__ float red[4];
  int m = blockIdx.x;
  int tid = threadIdx.x;
  if (tid < DIN_) xs[tid] = x[m*DIN_ + tid];
  __syncthreads();
  float v[2];
  #pragma unroll
  for (int r = 0; r < 2; ++r) {
    int n = tid + r*256;
    float acc = b1[n];
    #pragma unroll
    for (int k = 0; k < DIN_; ++k) acc += xs[k] * W1[k*D_ + n];
    v[r] = fmaxf(acc, 0.f);
  }
  float mean = block_reduce_sum(v[0] + v[1], red) * (1.f/D_);
  float d0 = v[0] - mean, d1 = v[1] - mean;
  float var = block_reduce_sum(d0*d0 + d1*d1, red) * (1.f/D_);
  float rstd = rsqrtf(var + 1e-5f);
  outb[(size_t)m*D_ + tid]       = f2bf(d0*rstd*g[tid]       + beta[tid]);
  outb[(size_t)m*D_ + tid + 256] = f2bf(d1*rstd*g[tid + 256] + beta[tid + 256]);
}

// ---------------- residual add + LayerNorm (res branch is bf16) ----------------
__global__ __launch_bounds__(256) void add_ln_kernel(const float* __restrict__ hin, const u16* __restrict__ res,
                              const float* __restrict__ g, const float* __restrict__ b,
                              float* __restrict__ outf, u16* __restrict__ outb) {
  __shared__ float red[4];
  int m = blockIdx.x;
  int tid = threadIdx.x;
  float v0 = hin[(size_t)m*D_ + tid]       + bf2f(res[(size_t)m*D_ + tid]);
  float v1 = hin[(size_t)m*D_ + tid + 256] + bf2f(res[(size_t)m*D_ + tid + 256]);
  float mean = block_reduce_sum(v0 + v1, red) * (1.f/D_);
  float d0 = v0 - mean, d1 = v1 - mean;
  float var = block_reduce_sum(d0*d0 + d1*d1, red) * (1.f/D_);
  float rstd = rsqrtf(var + 1e-5f);
  float o0 = d0*rstd*g[tid]       + b[tid];
  float o1 = d1*rstd*g[tid + 256] + b[tid + 256];
  outf[(size_t)m*D_ + tid]       = o0;
  outf[(size_t)m*D_ + tid + 256] = o1;
  outb[(size_t)m*D_ + tid]       = f2bf(o0);
  outb[(size_t)m*D_ + tid + 256] = f2bf(o1);
}

// ---------------- bf16 MFMA GEMM (2-phase pipelined):  C = A[M,K] @ Bt[N,K]^T ----------------
// EPI bits: 1=+bias, 2=relu, 4=+positional-encoding.  WF: write f32 Cf, WB: write bf16 Cb.
template<int BM, int BN, int EPI, bool WF, bool WB>
__global__ __launch_bounds__(256) void mgemm(const u16* __restrict__ A, const u16* __restrict__ Bt,
                            const float* __restrict__ bias, const float* __restrict__ extra,
                            float* __restrict__ Cf, u16* __restrict__ Cb,
                            int M, int N, int K) {
  __shared__ __align__(16) u16 As[2][BM*32];
  __shared__ __align__(16) u16 Bs[2][BN*32];
  const int WR = BM/2, WC = BN/2, MR = WR/16, NR = WC/16;
  // XCD-chunked swizzle (nwg % 8 == 0 for all our grids)
  int nx = gridDim.x;
  int nwg = nx * gridDim.y;
  int flat = blockIdx.y * nx + blockIdx.x;
  int wid = (flat & 7) * (nwg >> 3) + (flat >> 3);
  int bm = (wid / nx) * BM, bn = (wid % nx) * BN;
  int tid = threadIdx.x, w = tid >> 6, l = tid & 63;
  int wr = w >> 1, wc = w & 1;
  int lq = l & 15, lg = l >> 4;
  f32x4 acc[MR][NR];
  #pragma unroll
  for (int m = 0; m < MR; ++m)
    #pragma unroll
    for (int n = 0; n < NR; ++n) acc[m][n] = f32x4{0.f,0.f,0.f,0.f};

  int srow = w*16 + (l >> 2);
  int scol = (l & 3)*8;

  // prologue stage into buf 0
  #pragma unroll
  for (int i = 0; i < BM/64; ++i)
    GLOAD_LDS16(A + (size_t)(bm + i*64 + srow)*K + scol, &As[0][i*2048 + w*512]);
  #pragma unroll
  for (int i = 0; i < BN/64; ++i)
    GLOAD_LDS16(Bt + (size_t)(bn + i*64 + srow)*K + scol, &Bs[0][i*2048 + w*512]);

  int nk = K >> 5;
  #pragma unroll 1
  for (int t = 0; t < nk; ++t) {
    int buf = t & 1;
    __syncthreads();   // drains stage(buf); prior readers of buf^1 done
    if (t + 1 < nk) {  // stage next tile into buf^1 (flies during compute)
      int k0 = (t + 1) << 5;
      #pragma unroll
      for (int i = 0; i < BM/64; ++i)
        GLOAD_LDS16(A + (size_t)(bm + i*64 + srow)*K + k0 + scol, &As[buf^1][i*2048 + w*512]);
      #pragma unroll
      for (int i = 0; i < BN/64; ++i)
        GLOAD_LDS16(Bt + (size_t)(bn + i*64 + srow)*K + k0 + scol, &Bs[buf^1][i*2048 + w*512]);
    }
    bf16x8 af[MR], bfr[NR];
    #pragma unroll
    for (int m = 0; m < MR; ++m)
      af[m] = *(const bf16x8*)&As[buf][(wr*WR + m*16 + lq)*32 + lg*8];
    #pragma unroll
    for (int n = 0; n < NR; ++n)
      bfr[n] = *(const bf16x8*)&Bs[buf][(wc*WC + n*16 + lq)*32 + lg*8];
    #pragma unroll
    for (int m = 0; m < MR; ++m)
      #pragma unroll
      for (int n = 0; n < NR; ++n)
        acc[m][n] = __builtin_amdgcn_mfma_f32_16x16x32_bf16(af[m], bfr[n], acc[m][n], 0, 0, 0);
  }

  #pragma unroll
  for (int m = 0; m < MR; ++m) {
    #pragma unroll
    for (int n = 0; n < NR; ++n) {
      #pragma unroll
      for (int r = 0; r < 4; ++r) {
        int row = bm + wr*WR + m*16 + lg*4 + r;
        int col = bn + wc*WC + n*16 + lq;
        float v = acc[m][n][r];
        if (EPI & 1) v += bias[col];
        if (EPI & 2) v = fmaxf(v, 0.f);
        if (EPI & 4) {
          float fr  = __expf((float)(col & ~1) * PE_COEF);
          float arg = extra[row] * fr;
          v += (col & 1) ? cosf(arg) : sinf(arg);
        }
        if (WF) Cf[(size_t)row*N + col] = v;
        if (WB) Cb[(size_t)row*N + col] = f2bf(v);
      }
    }
  }
}

// ---------------- MFMA causal flash attention, KVBLK=64, paired q-tiles ----------------
// Flipped-PV layout: o holds O[q=lq][d], l via ones-MFMA, defer-max rescale,
// double-buffered LDS with register-staged async prefetch.
#define QS_ 1536
__global__ __launch_bounds__(256) void attn_kernel(const u16* __restrict__ Q, const u16* __restrict__ Kp,
                                                   const u16* __restrict__ V, u16* __restrict__ O) {
  __shared__ __align__(16) u16 Ks[2][64*72];     // [kv][d]  stride 72
  __shared__ __align__(16) u16 Vt[2][64*72];     // [d][kv]  stride 72
  __shared__ __align__(16) u16 Ps[4][16*72];     // per-wave [q][kv] stride 72
  // XCD-chunked swizzle: 64 consecutive work-ids (8 bh groups) per XCD
  int flat = blockIdx.y * 8 + blockIdx.x;        // grid (8,64), nwg=512
  int wid  = (flat & 7) * 64 + (flat >> 3);
  int pair = wid & 7, bh = wid >> 3;
  int b = bh >> 3, hh = bh & 7;
  int rowbase = b * L_, col0 = hh * 64;
  int tid = threadIdx.x, w = tid >> 6, l = tid & 63;
  int lq = l & 15, lg = l >> 4;

  int krow = tid >> 3, kseg = tid & 7;        // K staging
  int vg = tid >> 5, vd2 = (tid & 31) * 2;    // V staging (transpose via u32)

  u16x8 kr0, kr1;
  u32 vr[8];
  u16x8 oc16;
  #pragma unroll
  for (int i = 0; i < 8; ++i) oc16[i] = 0x3F80u;   // bf16 1.0
  const bf16x8 onesA = __builtin_bit_cast(bf16x8, oc16);

  #define LOADKV(t) { \
    kr0 = *(const u16x8*)&Kp[(size_t)(rowbase + (t)*64 + krow)*QS_ + col0 + kseg*8]; \
    kr1 = *(const u16x8*)&Kp[(size_t)(rowbase + (t)*64 + krow + 32)*QS_ + col0 + kseg*8]; \
    _Pragma("unroll") \
    for (int i_ = 0; i_ < 8; ++i_) \
      vr[i_] = *(const u32*)&V[(size_t)(rowbase + (t)*64 + vg*8 + i_)*QS_ + col0 + vd2]; }

  LOADKV(0);

  #pragma unroll 1
  for (int half = 0; half < 2; ++half) {
    int qt = half ? (15 - pair) : pair;
    int qrow = rowbase + qt*64 + w*16 + lq;
    bf16x8 qa0 = *(const bf16x8*)&Q[(size_t)qrow*QS_ + col0 + lg*8];
    bf16x8 qa1 = *(const bf16x8*)&Q[(size_t)qrow*QS_ + col0 + 32 + lg*8];
    float m_s[4];
    f32x4 o[4], o4;
    #pragma unroll
    for (int r = 0; r < 4; ++r) m_s[r] = -1e30f;
    #pragma unroll
    for (int n = 0; n < 4; ++n) o[n] = f32x4{0.f,0.f,0.f,0.f};
    o4 = f32x4{0.f,0.f,0.f,0.f};

    #pragma unroll 1
    for (int kt = 0; kt <= qt; ++kt) {
      int buf = kt & 1;
      __syncthreads();                         // A: readers of buf done; vreg loads drained
      // write staged regs -> LDS[buf]
      *(u16x8*)&Ks[buf][krow*72 + kseg*8]        = kr0;
      *(u16x8*)&Ks[buf][(krow + 32)*72 + kseg*8] = kr1;
      {
        u16x8 vlo, vhi;
        #pragma unroll
        for (int i = 0; i < 8; ++i) { vlo[i] = (u16)(vr[i] & 0xffffu); vhi[i] = (u16)(vr[i] >> 16); }
        *(u16x8*)&Vt[buf][vd2*72 + vg*8]     = vlo;
        *(u16x8*)&Vt[buf][(vd2+1)*72 + vg*8] = vhi;
      }
      __syncthreads();                         // B: writes visible
      // issue next-tile loads (fly during compute below)
      int nt = (kt < qt) ? (kt + 1) : (half == 0 ? 0 : -1);
      if (nt >= 0) LOADKV(nt);

      // S = Q K^T, scaled into log2 domain
      f32x4 t4[4];
      #pragma unroll
      for (int f = 0; f < 4; ++f) {
        bf16x8 k0 = *(const bf16x8*)&Ks[buf][(f*16 + lq)*72 + lg*8];
        bf16x8 k1 = *(const bf16x8*)&Ks[buf][(f*16 + lq)*72 + 32 + lg*8];
        f32x4 z = f32x4{0.f,0.f,0.f,0.f};
        z = __builtin_amdgcn_mfma_f32_16x16x32_bf16(qa0, k0, z, 0, 0, 0);
        z = __builtin_amdgcn_mfma_f32_16x16x32_bf16(qa1, k1, z, 0, 0, 0);
        #pragma unroll
        for (int r = 0; r < 4; ++r) t4[f][r] = z[r] * SC2;
      }
      if (kt == qt) {             // diagonal tile: causal mask
        #pragma unroll
        for (int f = 0; f < 4; ++f) {
          int kvg = f*16 + lq;
          #pragma unroll
          for (int r = 0; r < 4; ++r)
            if (kvg > w*16 + lg*4 + r) t4[f][r] = -1e30f;
        }
      }
      // row max per (lg,r); defer-max gate
      float tm[4];
      bool need = false;
      #pragma unroll
      for (int r = 0; r < 4; ++r) {
        float v = fmaxf(fmaxf(t4[0][r], t4[1][r]), fmaxf(t4[2][r], t4[3][r]));
        v = fmaxf(v, __shfl_xor(v, 1));
        v = fmaxf(v, __shfl_xor(v, 2));
        v = fmaxf(v, __shfl_xor(v, 4));
        v = fmaxf(v, __shfl_xor(v, 8));
        tm[r] = v;
        need = need || (v > m_s[r]);
      }
      if (__any(need)) {
        float corr[4];
        #pragma unroll
        for (int r = 0; r < 4; ++r) {
          float mn = fmaxf(m_s[r], tm[r]);
          corr[r] = __builtin_amdgcn_exp2f(m_s[r] - mn);
          m_s[r] = mn;
        }
        // broadcast corr to q=lq layout (o lives as O[q=lq][d])
        int bsrc = (lq >> 2)*16 + lq;
        float c0 = __shfl(corr[0], bsrc);
        float c1 = __shfl(corr[1], bsrc);
        float c2 = __shfl(corr[2], bsrc);
        float c3 = __shfl(corr[3], bsrc);
        float cb = (lq & 2) ? ((lq & 1) ? c3 : c2) : ((lq & 1) ? c1 : c0);
        #pragma unroll
        for (int n = 0; n < 4; ++n)
          #pragma unroll
          for (int r = 0; r < 4; ++r) o[n][r] *= cb;
        #pragma unroll
        for (int r = 0; r < 4; ++r) o4[r] *= cb;
      }
      // P = exp2(S - m), write to per-wave LDS in [q][kv]
      #pragma unroll
      for (int r = 0; r < 4; ++r) {
        int prow = (lg*4 + r)*72;
        Ps[w][prow + lq]      = f2bf_fast(__builtin_amdgcn_exp2f(t4[0][r] - m_s[r]));
        Ps[w][prow + 16 + lq] = f2bf_fast(__builtin_amdgcn_exp2f(t4[1][r] - m_s[r]));
        Ps[w][prow + 32 + lq] = f2bf_fast(__builtin_amdgcn_exp2f(t4[2][r] - m_s[r]));
        Ps[w][prow + 48 + lq] = f2bf_fast(__builtin_amdgcn_exp2f(t4[3][r] - m_s[r]));
      }
      // PV (flipped): o[d-rows][q-cols], l via ones-MFMA
      bf16x8 pB0 = *(const bf16x8*)&Ps[w][lq*72 + lg*8];
      bf16x8 pB1 = *(const bf16x8*)&Ps[w][lq*72 + 32 + lg*8];
      o4 = __builtin_amdgcn_mfma_f32_16x16x32_bf16(onesA, pB0, o4, 0, 0, 0);
      o4 = __builtin_amdgcn_mfma_f32_16x16x32_bf16(onesA, pB1, o4, 0, 0, 0);
      #pragma unroll
      for (int n = 0; n < 4; ++n) {
        bf16x8 vA0 = *(const bf16x8*)&Vt[buf][(n*16 + lq)*72 + lg*8];
        bf16x8 vA1 = *(const bf16x8*)&Vt[buf][(n*16 + lq)*72 + 32 + lg*8];
        o[n] = __builtin_amdgcn_mfma_f32_16x16x32_bf16(vA0, pB0, o[n], 0, 0, 0);
        o[n] = __builtin_amdgcn_mfma_f32_16x16x32_bf16(vA1, pB1, o[n], 0, 0, 0);
      }
    }
    // epilogue: one inv per lane (q = lq), packed 8B stores
    float inv = 1.f / o4[0];
    #pragma unroll
    for (int n = 0; n < 4; ++n) {
      u16x4 pk;
      #pragma unroll
      for (int r = 0; r < 4; ++r) pk[r] = f2bf(o[n][r] * inv);
      *(u16x4*)&O[(size_t)(rowbase + qt*64 + w*16 + lq)*D_ + col0 + n*16 + lg*4] = pk;
    }
  }
  #undef LOADKV
}

// ---------------- host ----------------
extern "C" void kernel_launch(void* const* d_in, const int* in_sizes, int n_in,
                              void* d_out, int out_size, void* d_ws, size_t ws_size,
                              hipStream_t stream) {
  (void)in_sizes; (void)n_in; (void)out_size; (void)ws_size;
  const float* x      = (const float*)d_in[0];
  const float* obs    = (const float*)d_in[2];
  const float* emb_w1 = (const float*)d_in[3];
  const float* emb_b1 = (const float*)d_in[4];
  const float* emb_g  = (const float*)d_in[5];
  const float* emb_be = (const float*)d_in[6];
  const float* emb_w2 = (const float*)d_in[7];
  const float* emb_b2 = (const float*)d_in[8];
  const float* wq  = (const float*)d_in[9];
  const float* wk  = (const float*)d_in[10];
  const float* wv  = (const float*)d_in[11];
  const float* wo  = (const float*)d_in[12];
  const float* bo  = (const float*)d_in[13];
  const float* fw1 = (const float*)d_in[14];
  const float* fb1 = (const float*)d_in[15];
  const float* fw2 = (const float*)d_in[16];
  const float* fb2 = (const float*)d_in[17];
  const float* g1  = (const float*)d_in[18];
  const float* b1  = (const float*)d_in[19];
  const float* g2  = (const float*)d_in[20];
  const float* b2  = (const float*)d_in[21];
  float* out = (float*)d_out;

  float* hf  = (float*)d_ws;                  // [M,D] f32 residual
  u16* hb    = (u16*)(hf + (size_t)M_*D_);    // [M,D] bf16 copy of hf
  u16* qkvb  = hb + (size_t)M_*D_;            // [M,3D] bf16 fused qkv
  u16* ob    = qkvb + (size_t)M_*3*D_;        // [M,D] bf16 (emb1 out / attn out)
  u16* ofb   = ob + (size_t)M_*D_;            // [M,D] bf16 branch out
  u16* fhb   = ofb + (size_t)M_*D_;           // [M,FF] bf16
  u16* qkvt  = fhb + (size_t)M_*FF_;          // [NL][3][D][D] bf16 (W^T)
  u16* wot   = qkvt + (size_t)18*DD_;         // [NL][D][D]
  u16* ew2t  = wot + (size_t)6*DD_;           // [D][D]
  u16* fw1t  = ew2t + (size_t)DD_;            // [NL][FF][D]
  u16* fw2t  = fw1t + (size_t)6*D_*FF_;       // [NL][D][FF]

  // weight transpose+convert
  transpose_k<<<dim3(16,16,6), 256, 0, stream>>>(wq, qkvt,          512, 512, DD_, 3*(size_t)DD_);
  transpose_k<<<dim3(16,16,6), 256, 0, stream>>>(wk, qkvt + DD_,    512, 512, DD_, 3*(size_t)DD_);
  transpose_k<<<dim3(16,16,6), 256, 0, stream>>>(wv, qkvt + 2*DD_,  512, 512, DD_, 3*(size_t)DD_);
  transpose_k<<<dim3(16,16,6), 256, 0, stream>>>(wo, wot,           512, 512, DD_, DD_);
  transpose_k<<<dim3(16,16,1), 256, 0, stream>>>(emb_w2, ew2t,      512, 512, DD_, DD_);
  transpose_k<<<dim3(2,16,6),  256, 0, stream>>>(fw1, fw1t,         512,  64, (size_t)D_*FF_, (size_t)D_*FF_);
  transpose_k<<<dim3(16,2,6),  256, 0, stream>>>(fw2, fw2t,          64, 512, (size_t)D_*FF_, (size_t)D_*FF_);

  emb1_ln_kernel<<<M_, 256, 0, stream>>>(x, emb_w1, emb_b1, emb_g, emb_be, ob);
  // h = ob @ emb_w2 + b2 + PE  -> hf (f32) + hb (bf16)
  mgemm<128,128,5,true,true><<<dim3(4,64), 256, 0, stream>>>(ob, ew2t, emb_b2, obs, hf, hb, M_, D_, D_);

  for (int i = 0; i < NL_; ++i) {
    // fused QKV projection: [M,1536]
    mgemm<128,128,0,false,true><<<dim3(12,64), 256, 0, stream>>>(hb, qkvt + (size_t)i*3*DD_,
        nullptr, nullptr, nullptr, qkvb, M_, 3*D_, D_);
    attn_kernel<<<dim3(8, B_*H_), 256, 0, stream>>>(qkvb, qkvb + D_, qkvb + 2*D_, ob);
    mgemm<128,128,1,false,true><<<dim3(4,64), 256, 0, stream>>>(ob, wot + (size_t)i*DD_,
        bo + i*D_, nullptr, nullptr, ofb, M_, D_, D_);
    add_ln_kernel<<<M_, 256, 0, stream>>>(hf, ofb, g1 + i*D_, b1 + i*D_, hf, hb);
    mgemm<64,64,3,false,true><<<dim3(1,128), 256, 0, stream>>>(hb, fw1t + (size_t)i*D_*FF_,
        fb1 + i*FF_, nullptr, nullptr, fhb, M_, FF_, D_);
    mgemm<128,128,1,false,true><<<dim3(4,64), 256, 0, stream>>>(fhb, fw2t + (size_t)i*D_*FF_,
        fb2 + i*D_, nullptr, nullptr, ofb, M_, D_, FF_);
    add_ln_kernel<<<M_, 256, 0, stream>>>(hf, ofb, g2 + i*D_, b2 + i*D_,
        (i == NL_-1) ? out : hf, hb);
  }
}

// Round 5
// 848.298 us; speedup vs baseline: 8.4686x; 1.0209x over previous
//
#include <hip/hip_runtime.h>
#include <math.h>

typedef unsigned short u16;
typedef unsigned int   u32;
typedef __bf16 bf16_t;
typedef bf16_t bf16x8 __attribute__((ext_vector_type(8)));
typedef float  f32x4  __attribute__((ext_vector_type(4)));
typedef u16    u16x8  __attribute__((ext_vector_type(8)));
typedef u16    u16x4  __attribute__((ext_vector_type(4)));

#define B_   8
#define L_   1024
#define DIN_ 32
#define D_   512
#define H_   8
#define NL_  6
#define FF_  64
#define M_   (B_*L_)    // 8192
#define DD_  (D_*D_)    // 262144

#define PE_COEF (-0.017988946039015984f)   // -ln(10000)/512
#define SC2     (0.18033688011112042f)     // 0.125 * log2(e)

__device__ __forceinline__ u16 f2bf(float f) {
  u32 u = __builtin_bit_cast(u32, f);
  u32 r = (u + 0x7FFFu + ((u >> 16) & 1u)) >> 16;
  return (u16)r;
}
__device__ __forceinline__ u16 f2bf_fast(float f) {   // positive values (P in [0,1])
  u32 u = __builtin_bit_cast(u32, f);
  return (u16)((u + 0x8000u) >> 16);
}
__device__ __forceinline__ float bf2f(u16 v) {
  u32 u = ((u32)v) << 16;
  return __builtin_bit_cast(float, u);
}

#define GLOAD_LDS16(gp, lp) \
  __builtin_amdgcn_global_load_lds((const __attribute__((address_space(1))) u32*)(gp), \
                                   (__attribute__((address_space(3))) u32*)(lp), 16, 0, 0)

// ---------------- block reduce (256 threads = 4 waves) ----------------
__device__ __forceinline__ float block_reduce_sum(float v, float* smem4) {
  #pragma unroll
  for (int off = 32; off > 0; off >>= 1) v += __shfl_down(v, off, 64);
  int wid = threadIdx.x >> 6;
  __syncthreads();
  if ((threadIdx.x & 63) == 0) smem4[wid] = v;
  __syncthreads();
  return smem4[0] + smem4[1] + smem4[2] + smem4[3];
}

// ---------------- weight transpose + f32->bf16:  W[K][N] -> Wt[N][K] ----------------
__global__ __launch_bounds__(256) void transpose_k(const float* __restrict__ W, u16* __restrict__ Wt,
                                                   int K, int N, size_t in_zs, size_t out_zs) {
  __shared__ float tile[32][33];
  size_t mi = (size_t)blockIdx.z * in_zs;
  size_t mo = (size_t)blockIdx.z * out_zs;
  int k0 = blockIdx.y * 32, n0 = blockIdx.x * 32;
  int tx = threadIdx.x & 31, ty = threadIdx.x >> 5;   // ty 0..7
  #pragma unroll
  for (int i = 0; i < 4; ++i)
    tile[ty + i*8][tx] = W[mi + (size_t)(k0 + ty + i*8)*N + n0 + tx];
  __syncthreads();
  #pragma unroll
  for (int i = 0; i < 4; ++i)
    Wt[mo + (size_t)(n0 + ty + i*8)*K + k0 + tx] = f2bf(tile[tx][ty + i*8]);
}

// ---------------- embedding MLP stage 1 + LayerNorm (bf16 out) ----------------
__global__ __launch_bounds__(256) void emb1_ln_kernel(const float* __restrict__ x, const float* __restrict__ W1,
                               const float* __restrict__ b1, const float* __restrict__ g,
                               const float* __restrict__ beta, u16* __restrict__ outb) {
  __shared__ float xs[DIN_];
  __shared__ float red[4];
  int m = blockIdx.x;
  int tid = threadIdx.x;
  if (tid < DIN_) xs[tid] = x[m*DIN_ + tid];
  __syncthreads();
  float v[2];
  #pragma unroll
  for (int r = 0; r < 2; ++r) {
    int n = tid + r*256;
    float acc = b1[n];
    #pragma unroll
    for (int k = 0; k < DIN_; ++k) acc += xs[k] * W1[k*D_ + n];
    v[r] = fmaxf(acc, 0.f);
  }
  float mean = block_reduce_sum(v[0] + v[1], red) * (1.f/D_);
  float d0 = v[0] - mean, d1 = v[1] - mean;
  float var = block_reduce_sum(d0*d0 + d1*d1, red) * (1.f/D_);
  float rstd = rsqrtf(var + 1e-5f);
  outb[(size_t)m*D_ + tid]       = f2bf(d0*rstd*g[tid]       + beta[tid]);
  outb[(size_t)m*D_ + tid + 256] = f2bf(d1*rstd*g[tid + 256] + beta[tid + 256]);
}

// ---------------- residual add + LayerNorm (res branch is bf16) ----------------
__global__ __launch_bounds__(256) void add_ln_kernel(const float* __restrict__ hin, const u16* __restrict__ res,
                              const float* __restrict__ g, const float* __restrict__ b,
                              float* __restrict__ outf, u16* __restrict__ outb) {
  __shared__ float red[4];
  int m = blockIdx.x;
  int tid = threadIdx.x;
  float v0 = hin[(size_t)m*D_ + tid]       + bf2f(res[(size_t)m*D_ + tid]);
  float v1 = hin[(size_t)m*D_ + tid + 256] + bf2f(res[(size_t)m*D_ + tid + 256]);
  float mean = block_reduce_sum(v0 + v1, red) * (1.f/D_);
  float d0 = v0 - mean, d1 = v1 - mean;
  float var = block_reduce_sum(d0*d0 + d1*d1, red) * (1.f/D_);
  float rstd = rsqrtf(var + 1e-5f);
  float o0 = d0*rstd*g[tid]       + b[tid];
  float o1 = d1*rstd*g[tid + 256] + b[tid + 256];
  outf[(size_t)m*D_ + tid]       = o0;
  outf[(size_t)m*D_ + tid + 256] = o1;
  outb[(size_t)m*D_ + tid]       = f2bf(o0);
  outb[(size_t)m*D_ + tid + 256] = f2bf(o1);
}

// ---------------- bf16 MFMA GEMM, depth-2 counted-vmcnt pipeline ----------------
// C = A[M,K] @ Bt[N,K]^T.  EPI bits: 1=+bias, 2=relu, 4=+PE.  WF: f32 out, WB: bf16 out.
template<int BM, int BN, int EPI, bool WF, bool WB>
__global__ __launch_bounds__(256) void mgemm(const u16* __restrict__ A, const u16* __restrict__ Bt,
                            const float* __restrict__ bias, const float* __restrict__ extra,
                            float* __restrict__ Cf, u16* __restrict__ Cb,
                            int M, int N, int K) {
  constexpr int NBUF = 3;
  constexpr int LPT = BM/64 + BN/64;         // global_load_lds per thread per stage
  __shared__ __align__(16) u16 As[NBUF][BM*32];
  __shared__ __align__(16) u16 Bs[NBUF][BN*32];
  const int WR = BM/2, WC = BN/2, MR = WR/16, NR = WC/16;
  // XCD-chunked swizzle (all grids have nwg % 8 == 0): contiguous bm-ranges per XCD
  int nx = gridDim.x;
  int nwg = nx * gridDim.y;
  int flat = blockIdx.y * nx + blockIdx.x;
  int wid = (flat & 7) * (nwg >> 3) + (flat >> 3);
  int bm = (wid / nx) * BM, bn = (wid % nx) * BN;
  int tid = threadIdx.x, w = tid >> 6, l = tid & 63;
  int wr = w >> 1, wc = w & 1;
  int lq = l & 15, lg = l >> 4;
  f32x4 acc[MR][NR];
  #pragma unroll
  for (int m = 0; m < MR; ++m)
    #pragma unroll
    for (int n = 0; n < NR; ++n) acc[m][n] = f32x4{0.f,0.f,0.f,0.f};

  int srow = w*16 + (l >> 2);
  int scol = (l & 3)*8;

  auto stage = [&](int t, int bi) {
    int k0 = t << 5;
    #pragma unroll
    for (int i = 0; i < BM/64; ++i)
      GLOAD_LDS16(A + (size_t)(bm + i*64 + srow)*K + k0 + scol, &As[bi][i*2048 + w*512]);
    #pragma unroll
    for (int i = 0; i < BN/64; ++i)
      GLOAD_LDS16(Bt + (size_t)(bn + i*64 + srow)*K + k0 + scol, &Bs[bi][i*2048 + w*512]);
  };

  int nk = K >> 5;
  stage(0, 0);
  if (nk > 1) stage(1, 1);
  int bi = 0;
  #pragma unroll 1
  for (int t = 0; t < nk; ++t) {
    // wait until stage(t) landed; keep stage(t+1) in flight (counted vmcnt, never 0 mid-loop)
    if (t + 1 < nk) {
      if constexpr (LPT == 2)      asm volatile("s_waitcnt vmcnt(2)" ::: "memory");
      else if constexpr (LPT == 3) asm volatile("s_waitcnt vmcnt(3)" ::: "memory");
      else if constexpr (LPT == 4) asm volatile("s_waitcnt vmcnt(4)" ::: "memory");
      else                         asm volatile("s_waitcnt vmcnt(0)" ::: "memory");
    } else {
      asm volatile("s_waitcnt vmcnt(0)" ::: "memory");
    }
    __builtin_amdgcn_s_barrier();            // all waves' stage(t) visible; compute(t-1) done
    __builtin_amdgcn_sched_barrier(0);       // fence: nothing hoists above the barrier
    if (t + 2 < nk) {
      int b2 = bi + 2; if (b2 >= NBUF) b2 -= NBUF;
      stage(t + 2, b2);                      // overwrites buf of t-1 (readers done)
    }
    bf16x8 af[MR], bfr[NR];
    #pragma unroll
    for (int m = 0; m < MR; ++m)
      af[m] = *(const bf16x8*)&As[bi][(wr*WR + m*16 + lq)*32 + lg*8];
    #pragma unroll
    for (int n = 0; n < NR; ++n)
      bfr[n] = *(const bf16x8*)&Bs[bi][(wc*WC + n*16 + lq)*32 + lg*8];
    #pragma unroll
    for (int m = 0; m < MR; ++m)
      #pragma unroll
      for (int n = 0; n < NR; ++n)
        acc[m][n] = __builtin_amdgcn_mfma_f32_16x16x32_bf16(af[m], bfr[n], acc[m][n], 0, 0, 0);
    bi = (bi + 1 == NBUF) ? 0 : bi + 1;
  }

  #pragma unroll
  for (int m = 0; m < MR; ++m) {
    #pragma unroll
    for (int n = 0; n < NR; ++n) {
      #pragma unroll
      for (int r = 0; r < 4; ++r) {
        int row = bm + wr*WR + m*16 + lg*4 + r;
        int col = bn + wc*WC + n*16 + lq;
        float v = acc[m][n][r];
        if (EPI & 1) v += bias[col];
        if (EPI & 2) v = fmaxf(v, 0.f);
        if (EPI & 4) {
          float fr  = __expf((float)(col & ~1) * PE_COEF);
          float arg = extra[row] * fr;
          v += (col & 1) ? cosf(arg) : sinf(arg);
        }
        if (WF) Cf[(size_t)row*N + col] = v;
        if (WB) Cb[(size_t)row*N + col] = f2bf(v);
      }
    }
  }
}

// ---------------- MFMA causal flash attention, KVBLK=64, paired q-tiles ----------------
// Flipped-PV layout: o holds O[q=lq][d], l via ones-MFMA, defer-max rescale,
// double-buffered LDS with register-staged async prefetch; setprio around MFMA clusters.
#define QS_ 1536
__global__ __launch_bounds__(256) void attn_kernel(const u16* __restrict__ Q, const u16* __restrict__ Kp,
                                                   const u16* __restrict__ V, u16* __restrict__ O) {
  __shared__ __align__(16) u16 Ks[2][64*72];     // [kv][d]  stride 72
  __shared__ __align__(16) u16 Vt[2][64*72];     // [d][kv]  stride 72
  __shared__ __align__(16) u16 Ps[4][16*72];     // per-wave [q][kv] stride 72
  int flat = blockIdx.y * 8 + blockIdx.x;        // grid (8,64), nwg=512
  int wid  = (flat & 7) * 64 + (flat >> 3);
  int pair = wid & 7, bh = wid >> 3;
  int b = bh >> 3, hh = bh & 7;
  int rowbase = b * L_, col0 = hh * 64;
  int tid = threadIdx.x, w = tid >> 6, l = tid & 63;
  int lq = l & 15, lg = l >> 4;

  int krow = tid >> 3, kseg = tid & 7;        // K staging
  int vg = tid >> 5, vd2 = (tid & 31) * 2;    // V staging (transpose via u32)

  u16x8 kr0, kr1;
  u32 vr[8];
  u16x8 oc16;
  #pragma unroll
  for (int i = 0; i < 8; ++i) oc16[i] = 0x3F80u;   // bf16 1.0
  const bf16x8 onesA = __builtin_bit_cast(bf16x8, oc16);

  #define LOADKV(t) { \
    kr0 = *(const u16x8*)&Kp[(size_t)(rowbase + (t)*64 + krow)*QS_ + col0 + kseg*8]; \
    kr1 = *(const u16x8*)&Kp[(size_t)(rowbase + (t)*64 + krow + 32)*QS_ + col0 + kseg*8]; \
    _Pragma("unroll") \
    for (int i_ = 0; i_ < 8; ++i_) \
      vr[i_] = *(const u32*)&V[(size_t)(rowbase + (t)*64 + vg*8 + i_)*QS_ + col0 + vd2]; }

  LOADKV(0);

  #pragma unroll 1
  for (int half = 0; half < 2; ++half) {
    int qt = half ? (15 - pair) : pair;
    int qrow = rowbase + qt*64 + w*16 + lq;
    bf16x8 qa0 = *(const bf16x8*)&Q[(size_t)qrow*QS_ + col0 + lg*8];
    bf16x8 qa1 = *(const bf16x8*)&Q[(size_t)qrow*QS_ + col0 + 32 + lg*8];
    float m_s[4];
    f32x4 o[4], o4;
    #pragma unroll
    for (int r = 0; r < 4; ++r) m_s[r] = -1e30f;
    #pragma unroll
    for (int n = 0; n < 4; ++n) o[n] = f32x4{0.f,0.f,0.f,0.f};
    o4 = f32x4{0.f,0.f,0.f,0.f};

    #pragma unroll 1
    for (int kt = 0; kt <= qt; ++kt) {
      int buf = kt & 1;
      __syncthreads();                         // A: readers of buf done; vreg loads drained
      *(u16x8*)&Ks[buf][krow*72 + kseg*8]        = kr0;
      *(u16x8*)&Ks[buf][(krow + 32)*72 + kseg*8] = kr1;
      {
        u16x8 vlo, vhi;
        #pragma unroll
        for (int i = 0; i < 8; ++i) { vlo[i] = (u16)(vr[i] & 0xffffu); vhi[i] = (u16)(vr[i] >> 16); }
        *(u16x8*)&Vt[buf][vd2*72 + vg*8]     = vlo;
        *(u16x8*)&Vt[buf][(vd2+1)*72 + vg*8] = vhi;
      }
      __syncthreads();                         // B: writes visible
      int nt = (kt < qt) ? (kt + 1) : (half == 0 ? 0 : -1);
      if (nt >= 0) LOADKV(nt);

      // S = Q K^T, scaled into log2 domain
      f32x4 t4[4];
      __builtin_amdgcn_s_setprio(1);
      #pragma unroll
      for (int f = 0; f < 4; ++f) {
        bf16x8 k0 = *(const bf16x8*)&Ks[buf][(f*16 + lq)*72 + lg*8];
        bf16x8 k1 = *(const bf16x8*)&Ks[buf][(f*16 + lq)*72 + 32 + lg*8];
        f32x4 z = f32x4{0.f,0.f,0.f,0.f};
        z = __builtin_amdgcn_mfma_f32_16x16x32_bf16(qa0, k0, z, 0, 0, 0);
        z = __builtin_amdgcn_mfma_f32_16x16x32_bf16(qa1, k1, z, 0, 0, 0);
        #pragma unroll
        for (int r = 0; r < 4; ++r) t4[f][r] = z[r] * SC2;
      }
      __builtin_amdgcn_s_setprio(0);
      if (kt == qt) {             // diagonal tile: causal mask
        #pragma unroll
        for (int f = 0; f < 4; ++f) {
          int kvg = f*16 + lq;
          #pragma unroll
          for (int r = 0; r < 4; ++r)
            if (kvg > w*16 + lg*4 + r) t4[f][r] = -1e30f;
        }
      }
      // row max per (lg,r); defer-max gate
      float tm[4];
      bool need = false;
      #pragma unroll
      for (int r = 0; r < 4; ++r) {
        float v = fmaxf(fmaxf(t4[0][r], t4[1][r]), fmaxf(t4[2][r], t4[3][r]));
        v = fmaxf(v, __shfl_xor(v, 1));
        v = fmaxf(v, __shfl_xor(v, 2));
        v = fmaxf(v, __shfl_xor(v, 4));
        v = fmaxf(v, __shfl_xor(v, 8));
        tm[r] = v;
        need = need || (v > m_s[r]);
      }
      if (__any(need)) {
        float corr[4];
        #pragma unroll
        for (int r = 0; r < 4; ++r) {
          float mn = fmaxf(m_s[r], tm[r]);
          corr[r] = __builtin_amdgcn_exp2f(m_s[r] - mn);
          m_s[r] = mn;
        }
        int bsrc = (lq >> 2)*16 + lq;
        float c0 = __shfl(corr[0], bsrc);
        float c1 = __shfl(corr[1], bsrc);
        float c2 = __shfl(corr[2], bsrc);
        float c3 = __shfl(corr[3], bsrc);
        float cb = (lq & 2) ? ((lq & 1) ? c3 : c2) : ((lq & 1) ? c1 : c0);
        #pragma unroll
        for (int n = 0; n < 4; ++n)
          #pragma unroll
          for (int r = 0; r < 4; ++r) o[n][r] *= cb;
        #pragma unroll
        for (int r = 0; r < 4; ++r) o4[r] *= cb;
      }
      // P = exp2(S - m), write to per-wave LDS in [q][kv]
      #pragma unroll
      for (int r = 0; r < 4; ++r) {
        int prow = (lg*4 + r)*72;
        Ps[w][prow + lq]      = f2bf_fast(__builtin_amdgcn_exp2f(t4[0][r] - m_s[r]));
        Ps[w][prow + 16 + lq] = f2bf_fast(__builtin_amdgcn_exp2f(t4[1][r] - m_s[r]));
        Ps[w][prow + 32 + lq] = f2bf_fast(__builtin_amdgcn_exp2f(t4[2][r] - m_s[r]));
        Ps[w][prow + 48 + lq] = f2bf_fast(__builtin_amdgcn_exp2f(t4[3][r] - m_s[r]));
      }
      // PV (flipped): o[d-rows][q-cols], l via ones-MFMA
      bf16x8 pB0 = *(const bf16x8*)&Ps[w][lq*72 + lg*8];
      bf16x8 pB1 = *(const bf16x8*)&Ps[w][lq*72 + 32 + lg*8];
      __builtin_amdgcn_s_setprio(1);
      o4 = __builtin_amdgcn_mfma_f32_16x16x32_bf16(onesA, pB0, o4, 0, 0, 0);
      o4 = __builtin_amdgcn_mfma_f32_16x16x32_bf16(onesA, pB1, o4, 0, 0, 0);
      #pragma unroll
      for (int n = 0; n < 4; ++n) {
        bf16x8 vA0 = *(const bf16x8*)&Vt[buf][(n*16 + lq)*72 + lg*8];
        bf16x8 vA1 = *(const bf16x8*)&Vt[buf][(n*16 + lq)*72 + 32 + lg*8];
        o[n] = __builtin_amdgcn_mfma_f32_16x16x32_bf16(vA0, pB0, o[n], 0, 0, 0);
        o[n] = __builtin_amdgcn_mfma_f32_16x16x32_bf16(vA1, pB1, o[n], 0, 0, 0);
      }
      __builtin_amdgcn_s_setprio(0);
    }
    // epilogue: one inv per lane (q = lq), packed 8B stores
    float inv = 1.f / o4[0];
    #pragma unroll
    for (int n = 0; n < 4; ++n) {
      u16x4 pk;
      #pragma unroll
      for (int r = 0; r < 4; ++r) pk[r] = f2bf(o[n][r] * inv);
      *(u16x4*)&O[(size_t)(rowbase + qt*64 + w*16 + lq)*D_ + col0 + n*16 + lg*4] = pk;
    }
  }
  #undef LOADKV
}

// ---------------- host ----------------
extern "C" void kernel_launch(void* const* d_in, const int* in_sizes, int n_in,
                              void* d_out, int out_size, void* d_ws, size_t ws_size,
                              hipStream_t stream) {
  (void)in_sizes; (void)n_in; (void)out_size; (void)ws_size;
  const float* x      = (const float*)d_in[0];
  const float* obs    = (const float*)d_in[2];
  const float* emb_w1 = (const float*)d_in[3];
  const float* emb_b1 = (const float*)d_in[4];
  const float* emb_g  = (const float*)d_in[5];
  const float* emb_be = (const float*)d_in[6];
  const float* emb_w2 = (const float*)d_in[7];
  const float* emb_b2 = (const float*)d_in[8];
  const float* wq  = (const float*)d_in[9];
  const float* wk  = (const float*)d_in[10];
  const float* wv  = (const float*)d_in[11];
  const float* wo  = (const float*)d_in[12];
  const float* bo  = (const float*)d_in[13];
  const float* fw1 = (const float*)d_in[14];
  const float* fb1 = (const float*)d_in[15];
  const float* fw2 = (const float*)d_in[16];
  const float* fb2 = (const float*)d_in[17];
  const float* g1  = (const float*)d_in[18];
  const float* b1  = (const float*)d_in[19];
  const float* g2  = (const float*)d_in[20];
  const float* b2  = (const float*)d_in[21];
  float* out = (float*)d_out;

  float* hf  = (float*)d_ws;                  // [M,D] f32 residual
  u16* hb    = (u16*)(hf + (size_t)M_*D_);    // [M,D] bf16 copy of hf
  u16* qkvb  = hb + (size_t)M_*D_;            // [M,3D] bf16 fused qkv
  u16* ob    = qkvb + (size_t)M_*3*D_;        // [M,D] bf16 (emb1 out / attn out)
  u16* ofb   = ob + (size_t)M_*D_;            // [M,D] bf16 branch out
  u16* fhb   = ofb + (size_t)M_*D_;           // [M,FF] bf16
  u16* qkvt  = fhb + (size_t)M_*FF_;          // [NL][3][D][D] bf16 (W^T)
  u16* wot   = qkvt + (size_t)18*DD_;         // [NL][D][D]
  u16* ew2t  = wot + (size_t)6*DD_;           // [D][D]
  u16* fw1t  = ew2t + (size_t)DD_;            // [NL][FF][D]
  u16* fw2t  = fw1t + (size_t)6*D_*FF_;       // [NL][D][FF]

  // weight transpose+convert
  transpose_k<<<dim3(16,16,6), 256, 0, stream>>>(wq, qkvt,          512, 512, DD_, 3*(size_t)DD_);
  transpose_k<<<dim3(16,16,6), 256, 0, stream>>>(wk, qkvt + DD_,    512, 512, DD_, 3*(size_t)DD_);
  transpose_k<<<dim3(16,16,6), 256, 0, stream>>>(wv, qkvt + 2*DD_,  512, 512, DD_, 3*(size_t)DD_);
  transpose_k<<<dim3(16,16,6), 256, 0, stream>>>(wo, wot,           512, 512, DD_, DD_);
  transpose_k<<<dim3(16,16,1), 256, 0, stream>>>(emb_w2, ew2t,      512, 512, DD_, DD_);
  transpose_k<<<dim3(2,16,6),  256, 0, stream>>>(fw1, fw1t,         512,  64, (size_t)D_*FF_, (size_t)D_*FF_);
  transpose_k<<<dim3(16,2,6),  256, 0, stream>>>(fw2, fw2t,          64, 512, (size_t)D_*FF_, (size_t)D_*FF_);

  emb1_ln_kernel<<<M_, 256, 0, stream>>>(x, emb_w1, emb_b1, emb_g, emb_be, ob);
  // h = ob @ emb_w2 + b2 + PE  -> hf (f32) + hb (bf16)
  mgemm<128,128,5,true,true><<<dim3(4,64), 256, 0, stream>>>(ob, ew2t, emb_b2, obs, hf, hb, M_, D_, D_);

  for (int i = 0; i < NL_; ++i) {
    // fused QKV projection: [M,1536]
    mgemm<128,128,0,false,true><<<dim3(12,64), 256, 0, stream>>>(hb, qkvt + (size_t)i*3*DD_,
        nullptr, nullptr, nullptr, qkvb, M_, 3*D_, D_);
    attn_kernel<<<dim3(8, B_*H_), 256, 0, stream>>>(qkvb, qkvb + D_, qkvb + 2*D_, ob);
    mgemm<128,128,1,false,true><<<dim3(4,64), 256, 0, stream>>>(ob, wot + (size_t)i*DD_,
        bo + i*D_, nullptr, nullptr, ofb, M_, D_, D_);
    add_ln_kernel<<<M_, 256, 0, stream>>>(hf, ofb, g1 + i*D_, b1 + i*D_, hf, hb);
    mgemm<64,64,3,false,true><<<dim3(1,128), 256, 0, stream>>>(hb, fw1t + (size_t)i*D_*FF_,
        fb1 + i*FF_, nullptr, nullptr, fhb, M_, FF_, D_);
    mgemm<128,128,1,false,true><<<dim3(4,64), 256, 0, stream>>>(fhb, fw2t + (size_t)i*D_*FF_,
        fb2 + i*D_, nullptr, nullptr, ofb, M_, D_, FF_);
    add_ln_kernel<<<M_, 256, 0, stream>>>(hf, ofb, g2 + i*D_, b2 + i*D_,
        (i == NL_-1) ? out : hf, hb);
  }
}